// Round 8
// baseline (272.126 us; speedup 1.0000x reference)
//
#include <hip/hip_runtime.h>
#include <math.h>

#define CIN 512
#define NCLS 10
#define KDIM 4608            // 512*9
#define NTOT 6400            // 256*25
#define MPAD 640
#define BK 128
#define NKT 36               // KDIM/BK
#define NABLK (5 * NKT)      // 180 A-tile blocks in pack_a
#define LN2PI_F 1.8378770664093453f

typedef __attribute__((ext_vector_type(8))) short bf16x8;
typedef __attribute__((ext_vector_type(4))) float f32x4;

typedef const __attribute__((address_space(1))) void* gas_ptr;
typedef __attribute__((address_space(3))) void* las_ptr;

__device__ __forceinline__ void async_copy16(const void* g, void* l) {
    __builtin_amdgcn_global_load_lds((gas_ptr)g, (las_ptr)l, 16, 0, 0);
}

__device__ __forceinline__ unsigned short f2bf(float f) {
    unsigned int u = __float_as_uint(f);
    u = (u + 0x7fffu + ((u >> 16) & 1u)) >> 16;   // RNE
    return (unsigned short)u;
}
__device__ __forceinline__ float fexp(float x) { return __expf(x); }
__device__ __forceinline__ float flog(float x) { return __logf(x); }

// ---------------------------------------------------------------------------
// pack_a: blocks [0,180): weights fp32 -> bf16 pre-tiled for the GEMM's LDS
// staging order. Blocks [180, 243): Wm fp32 -> bf16 (for em_kernel).
// Block 0 additionally computes the folded BN scale/bias.
// ---------------------------------------------------------------------------
__global__ __launch_bounds__(256) void pack_a_kernel(
    const float* __restrict__ w_pose, const float* __restrict__ w_a,
    const float* __restrict__ bn_p_g, const float* __restrict__ bn_p_b,
    const float* __restrict__ bn_p_m, const float* __restrict__ bn_p_v,
    const float* __restrict__ bn_a_g, const float* __restrict__ bn_a_b,
    const float* __restrict__ bn_a_m, const float* __restrict__ bn_a_v,
    const float* __restrict__ Wm,
    unsigned short* __restrict__ At, unsigned short* __restrict__ Wmb,
    float* __restrict__ sc, float* __restrict__ bi)
{
    const int blk = blockIdx.x;
    const int t = threadIdx.x;

    if (blk >= NABLK) {                          // ---- Wm bf16 packing ----
        const int chunk = (blk - NABLK) * 256 + t;   // 8 floats per chunk
        if (chunk < 16000) {
            const float4* s4 = reinterpret_cast<const float4*>(Wm + (size_t)chunk * 8);
            float4 x0 = s4[0], x1 = s4[1];
            int4 o;
            o.x = (int)f2bf(x0.x) | ((int)f2bf(x0.y) << 16);
            o.y = (int)f2bf(x0.z) | ((int)f2bf(x0.w) << 16);
            o.z = (int)f2bf(x1.x) | ((int)f2bf(x1.y) << 16);
            o.w = (int)f2bf(x1.z) | ((int)f2bf(x1.w) << 16);
            reinterpret_cast<int4*>(Wmb + (size_t)chunk * 8)[0] = o;
        }
        return;
    }

    const int mblk = blk / NKT;
    if (blk == 0) {
        for (int i = t; i < MPAD; i += 256) {
            float s = 0.f, b = 0.f;
            if (i < 512) {
                s = bn_p_g[i] / sqrtf(bn_p_v[i] + 1e-5f);
                b = bn_p_b[i] - bn_p_m[i] * s;
            } else if (i < 544) {
                const int j = i - 512;
                s = bn_a_g[j] / sqrtf(bn_a_v[j] + 1e-5f);
                b = bn_a_b[j] - bn_a_m[j] * s;
            }
            sc[i] = s; bi[i] = b;
        }
    }

    const int kt = blk - mblk * NKT;
    #pragma unroll
    for (int j = 0; j < 8; ++j) {
        const int c = t + j * 256;               // 0..2047
        const int kc8 = c >> 7, slot = c & 127;
        const int row = mblk * 128 + (slot ^ (kc8 << 2));
        const int k0 = (kt * 16 + kc8) * 8;
        float v[8] = {0.f,0.f,0.f,0.f,0.f,0.f,0.f,0.f};
        if (row < 512) {
            const float4* s4 = reinterpret_cast<const float4*>(w_pose + (size_t)row * KDIM + k0);
            float4 x0 = s4[0], x1 = s4[1];
            v[0]=x0.x; v[1]=x0.y; v[2]=x0.z; v[3]=x0.w;
            v[4]=x1.x; v[5]=x1.y; v[6]=x1.z; v[7]=x1.w;
        } else if (row < 544) {
            const float4* s4 = reinterpret_cast<const float4*>(w_a + (size_t)(row - 512) * KDIM + k0);
            float4 x0 = s4[0], x1 = s4[1];
            v[0]=x0.x; v[1]=x0.y; v[2]=x0.z; v[3]=x0.w;
            v[4]=x1.x; v[5]=x1.y; v[6]=x1.z; v[7]=x1.w;
        }
        int4 o;
        o.x = (int)f2bf(v[0]) | ((int)f2bf(v[1]) << 16);
        o.y = (int)f2bf(v[2]) | ((int)f2bf(v[3]) << 16);
        o.z = (int)f2bf(v[4]) | ((int)f2bf(v[5]) << 16);
        o.w = (int)f2bf(v[6]) | ((int)f2bf(v[7]) << 16);
        reinterpret_cast<int4*>(At + ((((size_t)blk) << 11) + c) * 8)[0] = o;
    }
}

// ---------------------------------------------------------------------------
// pack_b: im2col fp32->bf16 into the GEMM pre-tiled layout. 1024 threads.
// ---------------------------------------------------------------------------
__global__ __launch_bounds__(1024) void pack_b_kernel(
    const float* __restrict__ x, unsigned short* __restrict__ Bt)
{
    __shared__ __align__(16) float xs[CIN * 25];
    const int b = blockIdx.x;
    const int t = threadIdx.x;
    const float4* xb = reinterpret_cast<const float4*>(x + (size_t)b * (CIN * 25));
    for (int f4 = t; f4 < (CIN * 25) / 4; f4 += 1024)
        reinterpret_cast<float4*>(xs)[f4] = xb[f4];
    __syncthreads();

    for (int w = t; w < 25 * (KDIM / 8); w += 1024) {
        const int px = w / (KDIM / 8);
        const int ch = w - px * (KDIM / 8);
        const int py = px / 5, qx = px % 5;
        const int k0 = ch * 8;
        unsigned short v[8];
        #pragma unroll
        for (int j = 0; j < 8; ++j) {
            const int k = k0 + j;
            const int ci = k / 9;
            const int kk = k - ci * 9;
            const int dy = kk / 3, dx = kk - dy * 3;
            const int yy = py + dy - 1, xx = qx + dx - 1;
            const bool ok = (yy >= 0) & (yy < 5) & (xx >= 0) & (xx < 5);
            v[j] = ok ? f2bf(xs[ci * 25 + yy * 5 + xx]) : (unsigned short)0;
        }
        int4 o;
        o.x = (int)v[0] | ((int)v[1] << 16);
        o.y = (int)v[2] | ((int)v[3] << 16);
        o.z = (int)v[4] | ((int)v[5] << 16);
        o.w = (int)v[6] | ((int)v[7] << 16);
        const int n = b * 25 + px;
        const int nblk = n >> 7, nr = n & 127;
        const int kt = k0 >> 7;
        const int kc8 = (k0 >> 3) & 15;
        const int c = kc8 * 128 + (nr ^ (kc8 << 2));
        reinterpret_cast<int4*>(Bt + ((((size_t)(nblk * NKT + kt)) << 11) + c) * 8)[0] = o;
    }
}

// ---------------------------------------------------------------------------
// gemm: unchanged (128x128, 2 K-groups x (2x2) waves, 64x64 wave tile,
// BK=128 double-buffered, pre-tiled coalesced staging).
// ---------------------------------------------------------------------------
__global__ __launch_bounds__(512) void gemm_kernel(
    const unsigned short* __restrict__ At,
    const unsigned short* __restrict__ Bt,
    const float* __restrict__ sc, const float* __restrict__ bi,
    float* __restrict__ C)                  // [544][6400]
{
    __shared__ __align__(16) unsigned char smem[131072];
    const int t = threadIdx.x;
    const int mblk = blockIdx.x, nblk = blockIdx.y;
    const int m0 = mblk * 128, n0 = nblk * 128;
    const int lane = t & 63, w = t >> 6;
    const int g = w >> 2, wq = w & 3;
    const int wm = wq >> 1, wn = wq & 1;
    const int row16 = lane & 15, quad = lane >> 4;

    f32x4 acc[4][4] = {};

    const unsigned short* gAbase = At + (((size_t)mblk * NKT) << 14);
    const unsigned short* gBbase = Bt + (((size_t)nblk * NKT) << 14);

    #define STAGE(kt, s)                                                      \
    {                                                                         \
        unsigned short* As_ = (unsigned short*)(smem + (s) * 65536);          \
        unsigned short* Bs_ = As_ + 16384;                                    \
        const unsigned short* ga = gAbase + ((size_t)(kt) << 14);             \
        const unsigned short* gb = gBbase + ((size_t)(kt) << 14);             \
        _Pragma("unroll")                                                     \
        for (int j = 0; j < 4; ++j) {                                         \
            async_copy16(ga + ((size_t)(j * 512 + t) << 3),                   \
                         As_ + ((size_t)(j * 512 + w * 64) << 3));            \
            async_copy16(gb + ((size_t)(j * 512 + t) << 3),                   \
                         Bs_ + ((size_t)(j * 512 + w * 64) << 3));            \
        }                                                                     \
    }

    #define COMPUTE(s)                                                        \
    {                                                                         \
        const unsigned short* As_ = (const unsigned short*)(smem + (s) * 65536);\
        const unsigned short* Bs_ = As_ + 16384;                              \
        _Pragma("unroll")                                                     \
        for (int ks = 0; ks < 2; ++ks) {                                      \
            const int kc8b = g * 8 + ks * 4 + quad;                           \
            const int sw = kc8b << 2;                                         \
            bf16x8 af[4], bfr[4];                                             \
            _Pragma("unroll")                                                 \
            for (int mt = 0; mt < 4; ++mt)                                    \
                af[mt] = *reinterpret_cast<const bf16x8*>(                    \
                    &As_[(size_t)(kc8b * 128 + ((wm * 64 + mt * 16 + row16) ^ sw)) * 8]);\
            _Pragma("unroll")                                                 \
            for (int nt = 0; nt < 4; ++nt)                                    \
                bfr[nt] = *reinterpret_cast<const bf16x8*>(                   \
                    &Bs_[(size_t)(kc8b * 128 + ((wn * 64 + nt * 16 + row16) ^ sw)) * 8]);\
            _Pragma("unroll")                                                 \
            for (int mt = 0; mt < 4; ++mt)                                    \
                _Pragma("unroll")                                             \
                for (int nt = 0; nt < 4; ++nt)                                \
                    acc[mt][nt] = __builtin_amdgcn_mfma_f32_16x16x32_bf16(    \
                        af[mt], bfr[nt], acc[mt][nt], 0, 0, 0);               \
        }                                                                     \
    }

    STAGE(0, 0);
    for (int kt = 0; kt < NKT; ++kt) {
        __syncthreads();
        if (kt + 1 < NKT) STAGE(kt + 1, (kt + 1) & 1);
        COMPUTE(kt & 1);
    }
    #undef STAGE
    #undef COMPUTE

    float* mb = (float*)smem;
    #pragma unroll
    for (int rnd = 0; rnd < 2; ++rnd) {
        __syncthreads();
        if (g == 1 && (wq >> 1) == rnd) {
            f32x4* dst = (f32x4*)(mb + (wq & 1) * 4096);
            #pragma unroll
            for (int i = 0; i < 16; ++i)
                dst[i * 64 + lane] = acc[i >> 2][i & 3];
        }
        __syncthreads();
        if (g == 0 && (wq >> 1) == rnd) {
            const f32x4* src = (const f32x4*)(mb + (wq & 1) * 4096);
            #pragma unroll
            for (int i = 0; i < 16; ++i)
                acc[i >> 2][i & 3] += src[i * 64 + lane];
        }
    }

    if (g == 0) {
        #pragma unroll
        for (int mt = 0; mt < 4; ++mt) {
            const int mbase = m0 + wm * 64 + mt * 16 + quad * 4;
            if (mbase >= 544) continue;
            #pragma unroll
            for (int rg = 0; rg < 4; ++rg) {
                const int m = mbase + rg;
                const float s = sc[m], bbx = bi[m];
                const bool is_a = (m >= 512);
                #pragma unroll
                for (int nt = 0; nt < 4; ++nt) {
                    const int n = n0 + wn * 64 + nt * 16 + row16;
                    float v = fmaf(acc[mt][nt][rg], s, bbx);
                    if (is_a) v = 1.f / (1.f + fexp(-v));
                    C[(size_t)m * NTOT + n] = v;
                }
            }
        }
    }
}

// ---------------------------------------------------------------------------
// EM routing v4: 640 threads, one block per batch.
//  phase S (stats): threads (h,c,a) own p in [8h,8h+8) over all 25 kk.
//  phase A (ln_p):  threads (h,c,a) own kk-half, full 16 p; mu/i2s from the
//                   muis LDS table (broadcast reads), so no 16-wide register
//                   state anywhere -> no spills.
//  phase R: softmax once per (c,m), staged in regs, written in-place into lnq.
//  Wm (bf16) + pose loads explicitly software-pipelined (prefetch kk+1).
// ---------------------------------------------------------------------------
__device__ __forceinline__ void unpack16(const int4& w0, const int4& w1, float* wv) {
    const unsigned int u[8] = {(unsigned)w0.x,(unsigned)w0.y,(unsigned)w0.z,(unsigned)w0.w,
                               (unsigned)w1.x,(unsigned)w1.y,(unsigned)w1.z,(unsigned)w1.w};
    #pragma unroll
    for (int i = 0; i < 8; ++i) {
        wv[2*i]   = __uint_as_float(u[i] << 16);
        wv[2*i+1] = __uint_as_float(u[i] & 0xFFFF0000u);
    }
}

__global__ __launch_bounds__(640, 1) void em_kernel(
    const float* __restrict__ C,
    const unsigned short* __restrict__ Wmb,   // (800,10,16) bf16
    const float* __restrict__ beta_u, const float* __restrict__ beta_a,
    float* __restrict__ out)                  // (256,10)
{
    __shared__ __align__(16) float psh[25][32][20];   // 64 KB  pose [kk][a][16+pad]
    __shared__ float aush[800];                        // 3.2 KB
    __shared__ float lnq[NCLS][800];                   // 32 KB (ln_ap -> rw in place)
    __shared__ float2 muis[NCLS][16];                  // mu, 0.5/sigma^2
    __shared__ float costp[2][NCLS];
    __shared__ float slgp[2][NCLS];
    __shared__ float Kc_sh[NCLS];
    __shared__ float aout_sh[NCLS];

    const int b = blockIdx.x, t = threadIdx.x;
    const int h = (t >= 320) ? 1 : 0;
    const int th = t - h * 320;
    const int c = th >> 5, a = th & 31;
    const int k0 = h ? 13 : 0;
    const int nk = h ? 12 : 13;

    // stage pose fp32: C row c2 (0..511) -> psh[px][c2>>4][c2&15]
    const float* pb = C + (size_t)b * 25;
    for (int f = t; f < 12800; f += 640) {
        const int c2 = f / 25, px = f - c2 * 25;
        psh[px][c2 >> 4][c2 & 15] = pb[(size_t)c2 * NTOT + px];
    }
    const float* ab = C + (size_t)512 * NTOT + (size_t)b * 25;
    for (int f = t; f < 800; f += 640) {
        const int ci = f / 25, px = f - ci * 25;
        aush[px * 32 + ci] = ab[(size_t)ci * NTOT + px];
    }
    __syncthreads();

    const float bu = beta_u[c], ba = beta_a[c];
    const unsigned short* wbase = Wmb + ((size_t)a * NCLS + c) * 16;  // + kk*5120

    float p95 = 1.f;
    for (int it = 0; it < 3; ++it) {
        p95 *= 0.95f;
        const float lam = 0.01f * (1.f - p95);

        if (it > 0) {
            // ---- phase A: full-16 ln_p for this thread's kk-half ----
            const float KcL = Kc_sh[c];
            const unsigned short* wp = wbase + (size_t)k0 * 5120;
            int4 wr0 = *reinterpret_cast<const int4*>(wp);
            int4 wr1 = *reinterpret_cast<const int4*>(wp + 8);
            for (int i = 0; i < nk; ++i) {
                const int kk = k0 + i;
                const int4 w0 = wr0, w1 = wr1;
                if (i + 1 < nk) {
                    const unsigned short* wn = wbase + (size_t)(kk + 1) * 5120;
                    wr0 = *reinterpret_cast<const int4*>(wn);
                    wr1 = *reinterpret_cast<const int4*>(wn + 8);
                }
                const float4 q0 = *reinterpret_cast<const float4*>(&psh[kk][a][0]);
                const float4 q1 = *reinterpret_cast<const float4*>(&psh[kk][a][4]);
                const float4 q2 = *reinterpret_cast<const float4*>(&psh[kk][a][8]);
                const float4 q3 = *reinterpret_cast<const float4*>(&psh[kk][a][12]);
                const float pm[16] = {q0.x,q0.y,q0.z,q0.w, q1.x,q1.y,q1.z,q1.w,
                                      q2.x,q2.y,q2.z,q2.w, q3.x,q3.y,q3.z,q3.w};
                float wv[16];
                unpack16(w0, w1, wv);
                float q = KcL;
                #pragma unroll
                for (int r = 0; r < 4; ++r) {
                    #pragma unroll
                    for (int s = 0; s < 4; ++s) {
                        float v = 0.f;
                        #pragma unroll
                        for (int t4 = 0; t4 < 4; ++t4)
                            v = fmaf(pm[r*4+t4], wv[t4*4+s], v);
                        const float2 mi = muis[c][r*4+s];
                        const float d = v - mi.x;
                        q = fmaf(-d * d, mi.y, q);
                    }
                }
                lnq[c][kk * 32 + a] = q;
            }
            __syncthreads();

            // ---- phase R: softmax once per (c,m); in-place into lnq ----
            float rst[13];
            #pragma unroll
            for (int i = 0; i < 13; ++i) {
                if (i < nk) {
                    const int m = (k0 + i) * 32 + a;
                    float qv[NCLS];
                    #pragma unroll
                    for (int cc = 0; cc < NCLS; ++cc) qv[cc] = lnq[cc][m];
                    float mx = qv[0];
                    #pragma unroll
                    for (int cc = 1; cc < NCLS; ++cc) mx = fmaxf(mx, qv[cc]);
                    float den = 0.f;
                    #pragma unroll
                    for (int cc = 0; cc < NCLS; ++cc) den += fexp(qv[cc] - mx);
                    rst[i] = fexp(qv[c] - mx) * __builtin_amdgcn_rcpf(den) * aush[m];
                }
            }
            __syncthreads();
            #pragma unroll
            for (int i = 0; i < 13; ++i)
                if (i < nk) lnq[c][(k0 + i) * 32 + a] = rst[i];
            __syncthreads();
        }

        // ---- phase S: stats over this thread's 8 p-components, all 25 kk ----
        const float* rwp = (it == 0) ? aush : &lnq[c][0];
        float S0 = 0.f, S1[8], S2[8];
        #pragma unroll
        for (int j = 0; j < 8; ++j) { S1[j] = 0.f; S2[j] = 0.f; }

        int4 wr0 = *reinterpret_cast<const int4*>(wbase);
        int4 wr1 = *reinterpret_cast<const int4*>(wbase + 8);
        float4 pr0 = *reinterpret_cast<const float4*>(&psh[0][a][h * 8]);
        float4 pr1 = *reinterpret_cast<const float4*>(&psh[0][a][h * 8 + 4]);
        for (int kk = 0; kk < 25; ++kk) {
            const int4 w0 = wr0, w1 = wr1;
            const float4 p0 = pr0, p1 = pr1;
            const float rw = rwp[kk * 32 + a];
            if (kk < 24) {
                const unsigned short* wn = wbase + (size_t)(kk + 1) * 5120;
                wr0 = *reinterpret_cast<const int4*>(wn);
                wr1 = *reinterpret_cast<const int4*>(wn + 8);
                pr0 = *reinterpret_cast<const float4*>(&psh[kk + 1][a][h * 8]);
                pr1 = *reinterpret_cast<const float4*>(&psh[kk + 1][a][h * 8 + 4]);
            }
            float wv[16];
            unpack16(w0, w1, wv);
            const float pm8[8] = {p0.x,p0.y,p0.z,p0.w, p1.x,p1.y,p1.z,p1.w};
            S0 += rw;
            #pragma unroll
            for (int jr = 0; jr < 2; ++jr) {
                #pragma unroll
                for (int s = 0; s < 4; ++s) {
                    float v = 0.f;
                    #pragma unroll
                    for (int t4 = 0; t4 < 4; ++t4)
                        v = fmaf(pm8[jr*4+t4], wv[t4*4+s], v);
                    const int j = jr * 4 + s;
                    const float rv = rw * v;
                    S1[j] += rv;
                    S2[j] = fmaf(rv, v, S2[j]);
                }
            }
        }

        // butterfly over the 32 a-lanes (stays within half-wave)
        #pragma unroll
        for (int off = 16; off >= 1; off >>= 1) {
            S0 += __shfl_xor(S0, off);
            #pragma unroll
            for (int j = 0; j < 8; ++j) {
                S1[j] += __shfl_xor(S1[j], off);
                S2[j] += __shfl_xor(S2[j], off);
            }
        }

        // per-half epilogue (both h groups hold the SAME full S0)
        if (a == 0) {
            const float s0e = S0 + 1e-12f;
            const float inv = 1.f / s0e;
            float cost_ = 0.f, slg_ = 0.f;
            #pragma unroll
            for (int j = 0; j < 8; ++j) {
                const float mu_ = S1[j] * inv;
                const float sg = (S2[j] - 2.f * mu_ * S1[j] + mu_ * mu_ * S0) * inv
                                 + 1e-12f;
                cost_ += bu + 0.5f * flog(sg);
                slg_ += flog(sg * LN2PI_F);
                muis[c][h * 8 + j] = make_float2(mu_, 0.5f / sg);
            }
            costp[h][c] = cost_;
            slgp[h][c] = slg_;
        }
        __syncthreads();
        if (a == 0 && h == 0) {
            const float costsum = (costp[0][c] + costp[1][c]) * S0;
            const float aout = 1.f / (1.f + fexp(-(lam * (ba - costsum))));
            aout_sh[c] = aout;
            Kc_sh[c] = flog(aout) - 0.5f * (slgp[0][c] + slgp[1][c]);
        }
        __syncthreads();
    }

    if (t < NCLS) {
        float s = 0.f;
        #pragma unroll
        for (int cc = 0; cc < NCLS; ++cc) s += aout_sh[cc];
        out[b * NCLS + t] = flog(aout_sh[t] / s);
    }
}

// ---------------------------------------------------------------------------
extern "C" void kernel_launch(void* const* d_in, const int* in_sizes, int n_in,
                              void* d_out, int out_size, void* d_ws, size_t ws_size,
                              hipStream_t stream) {
    const float* x      = (const float*)d_in[0];
    const float* w_a    = (const float*)d_in[1];
    const float* w_pose = (const float*)d_in[2];
    const float* bn_a_g = (const float*)d_in[3];
    const float* bn_a_b = (const float*)d_in[4];
    const float* bn_a_m = (const float*)d_in[5];
    const float* bn_a_v = (const float*)d_in[6];
    const float* bn_p_g = (const float*)d_in[7];
    const float* bn_p_b = (const float*)d_in[8];
    const float* bn_p_m = (const float*)d_in[9];
    const float* bn_p_v = (const float*)d_in[10];
    const float* Wm     = (const float*)d_in[11];
    const float* beta_u = (const float*)d_in[12];
    const float* beta_a = (const float*)d_in[13];
    float* out = (float*)d_out;

    char* p = (char*)d_ws;
    unsigned short* At  = (unsigned short*)p;  p += (size_t)MPAD * KDIM * 2;
    unsigned short* Bt  = (unsigned short*)p;  p += (size_t)NTOT * KDIM * 2;
    unsigned short* Wmb = (unsigned short*)p;  p += (size_t)800 * NCLS * 16 * 2;
    float* C  = (float*)p;                     p += (size_t)544 * NTOT * 4;
    float* sc = (float*)p;                     p += MPAD * 4;
    float* bi = (float*)p;                     p += MPAD * 4;

    pack_a_kernel<<<NABLK + 63, 256, 0, stream>>>(w_pose, w_a,
                                                  bn_p_g, bn_p_b, bn_p_m, bn_p_v,
                                                  bn_a_g, bn_a_b, bn_a_m, bn_a_v,
                                                  Wm, At, Wmb, sc, bi);
    pack_b_kernel<<<256, 1024, 0, stream>>>(x, Bt);
    dim3 gg(MPAD / 128, NTOT / 128);
    gemm_kernel<<<gg, 512, 0, stream>>>(At, Bt, sc, bi, C);
    em_kernel<<<256, 640, 0, stream>>>(C, Wmb, beta_u, beta_a, out);
}

// Round 9
// 258.017 us; speedup vs baseline: 1.0547x; 1.0547x over previous
//
#include <hip/hip_runtime.h>
#include <math.h>

#define CIN 512
#define NCLS 10
#define KDIM 4608            // 512*9
#define NTOT 6400            // 256*25
#define MPAD 640
#define BK 128
#define NKT 36               // KDIM/BK
#define NABLK (5 * NKT)      // 180 A-tile blocks in pack_a
#define LN2PI_F 1.8378770664093453f

typedef __attribute__((ext_vector_type(8))) short bf16x8;
typedef __attribute__((ext_vector_type(4))) float f32x4;

typedef const __attribute__((address_space(1))) void* gas_ptr;
typedef __attribute__((address_space(3))) void* las_ptr;

__device__ __forceinline__ void async_copy16(const void* g, void* l) {
    __builtin_amdgcn_global_load_lds((gas_ptr)g, (las_ptr)l, 16, 0, 0);
}

__device__ __forceinline__ unsigned short f2bf(float f) {
    unsigned int u = __float_as_uint(f);
    u = (u + 0x7fffu + ((u >> 16) & 1u)) >> 16;   // RNE
    return (unsigned short)u;
}
__device__ __forceinline__ float bf2f(unsigned short s) {
    return __uint_as_float(((unsigned int)s) << 16);
}
__device__ __forceinline__ float fexp(float x) { return __expf(x); }
__device__ __forceinline__ float flog(float x) { return __logf(x); }

// ---------------------------------------------------------------------------
// pack_a: blocks [0,180): weights fp32 -> bf16 pre-tiled for the GEMM's LDS
// staging order. Blocks [180, 243): Wm fp32 -> bf16 (for em_kernel).
// Block 0 additionally computes the folded BN scale/bias.
// ---------------------------------------------------------------------------
__global__ __launch_bounds__(256) void pack_a_kernel(
    const float* __restrict__ w_pose, const float* __restrict__ w_a,
    const float* __restrict__ bn_p_g, const float* __restrict__ bn_p_b,
    const float* __restrict__ bn_p_m, const float* __restrict__ bn_p_v,
    const float* __restrict__ bn_a_g, const float* __restrict__ bn_a_b,
    const float* __restrict__ bn_a_m, const float* __restrict__ bn_a_v,
    const float* __restrict__ Wm,
    unsigned short* __restrict__ At, unsigned short* __restrict__ Wmb,
    float* __restrict__ sc, float* __restrict__ bi)
{
    const int blk = blockIdx.x;
    const int t = threadIdx.x;

    if (blk >= NABLK) {                          // ---- Wm bf16 packing ----
        const int chunk = (blk - NABLK) * 256 + t;   // 8 floats per chunk
        if (chunk < 16000) {
            const float4* s4 = reinterpret_cast<const float4*>(Wm + (size_t)chunk * 8);
            float4 x0 = s4[0], x1 = s4[1];
            int4 o;
            o.x = (int)f2bf(x0.x) | ((int)f2bf(x0.y) << 16);
            o.y = (int)f2bf(x0.z) | ((int)f2bf(x0.w) << 16);
            o.z = (int)f2bf(x1.x) | ((int)f2bf(x1.y) << 16);
            o.w = (int)f2bf(x1.z) | ((int)f2bf(x1.w) << 16);
            reinterpret_cast<int4*>(Wmb + (size_t)chunk * 8)[0] = o;
        }
        return;
    }

    const int mblk = blk / NKT;
    if (blk == 0) {
        for (int i = t; i < MPAD; i += 256) {
            float s = 0.f, b = 0.f;
            if (i < 512) {
                s = bn_p_g[i] / sqrtf(bn_p_v[i] + 1e-5f);
                b = bn_p_b[i] - bn_p_m[i] * s;
            } else if (i < 544) {
                const int j = i - 512;
                s = bn_a_g[j] / sqrtf(bn_a_v[j] + 1e-5f);
                b = bn_a_b[j] - bn_a_m[j] * s;
            }
            sc[i] = s; bi[i] = b;
        }
    }

    const int kt = blk - mblk * NKT;
    #pragma unroll
    for (int j = 0; j < 8; ++j) {
        const int c = t + j * 256;               // 0..2047
        const int kc8 = c >> 7, slot = c & 127;
        const int row = mblk * 128 + (slot ^ (kc8 << 2));
        const int k0 = (kt * 16 + kc8) * 8;
        float v[8] = {0.f,0.f,0.f,0.f,0.f,0.f,0.f,0.f};
        if (row < 512) {
            const float4* s4 = reinterpret_cast<const float4*>(w_pose + (size_t)row * KDIM + k0);
            float4 x0 = s4[0], x1 = s4[1];
            v[0]=x0.x; v[1]=x0.y; v[2]=x0.z; v[3]=x0.w;
            v[4]=x1.x; v[5]=x1.y; v[6]=x1.z; v[7]=x1.w;
        } else if (row < 544) {
            const float4* s4 = reinterpret_cast<const float4*>(w_a + (size_t)(row - 512) * KDIM + k0);
            float4 x0 = s4[0], x1 = s4[1];
            v[0]=x0.x; v[1]=x0.y; v[2]=x0.z; v[3]=x0.w;
            v[4]=x1.x; v[5]=x1.y; v[6]=x1.z; v[7]=x1.w;
        }
        int4 o;
        o.x = (int)f2bf(v[0]) | ((int)f2bf(v[1]) << 16);
        o.y = (int)f2bf(v[2]) | ((int)f2bf(v[3]) << 16);
        o.z = (int)f2bf(v[4]) | ((int)f2bf(v[5]) << 16);
        o.w = (int)f2bf(v[6]) | ((int)f2bf(v[7]) << 16);
        reinterpret_cast<int4*>(At + ((((size_t)blk) << 11) + c) * 8)[0] = o;
    }
}

// ---------------------------------------------------------------------------
// pack_b: im2col fp32->bf16 into the GEMM pre-tiled layout. 1024 threads.
// ---------------------------------------------------------------------------
__global__ __launch_bounds__(1024) void pack_b_kernel(
    const float* __restrict__ x, unsigned short* __restrict__ Bt)
{
    __shared__ __align__(16) float xs[CIN * 25];
    const int b = blockIdx.x;
    const int t = threadIdx.x;
    const float4* xb = reinterpret_cast<const float4*>(x + (size_t)b * (CIN * 25));
    for (int f4 = t; f4 < (CIN * 25) / 4; f4 += 1024)
        reinterpret_cast<float4*>(xs)[f4] = xb[f4];
    __syncthreads();

    for (int w = t; w < 25 * (KDIM / 8); w += 1024) {
        const int px = w / (KDIM / 8);
        const int ch = w - px * (KDIM / 8);
        const int py = px / 5, qx = px % 5;
        const int k0 = ch * 8;
        unsigned short v[8];
        #pragma unroll
        for (int j = 0; j < 8; ++j) {
            const int k = k0 + j;
            const int ci = k / 9;
            const int kk = k - ci * 9;
            const int dy = kk / 3, dx = kk - dy * 3;
            const int yy = py + dy - 1, xx = qx + dx - 1;
            const bool ok = (yy >= 0) & (yy < 5) & (xx >= 0) & (xx < 5);
            v[j] = ok ? f2bf(xs[ci * 25 + yy * 5 + xx]) : (unsigned short)0;
        }
        int4 o;
        o.x = (int)v[0] | ((int)v[1] << 16);
        o.y = (int)v[2] | ((int)v[3] << 16);
        o.z = (int)v[4] | ((int)v[5] << 16);
        o.w = (int)v[6] | ((int)v[7] << 16);
        const int n = b * 25 + px;
        const int nblk = n >> 7, nr = n & 127;
        const int kt = k0 >> 7;
        const int kc8 = (k0 >> 3) & 15;
        const int c = kc8 * 128 + (nr ^ (kc8 << 2));
        reinterpret_cast<int4*>(Bt + ((((size_t)(nblk * NKT + kt)) << 11) + c) * 8)[0] = o;
    }
}

// ---------------------------------------------------------------------------
// gemm: 128x128, 2 K-groups x (2x2) waves, 64x64 wave tile, BK=128
// double-buffered, pre-tiled coalesced staging. NEW vs R8:
//  - 1-D grid 250 with XCD-aware mapping: the 5 blocks sharing a B-panel
//    have blockIdx differing by 8 -> same XCD (round-robin) -> one L2 copy.
//  - C split: pose rows (m<512) stored bf16 (Cp), a-rows fp32 (Ca).
// ---------------------------------------------------------------------------
__global__ __launch_bounds__(512) void gemm_kernel(
    const unsigned short* __restrict__ At,
    const unsigned short* __restrict__ Bt,
    const float* __restrict__ sc, const float* __restrict__ bi,
    unsigned short* __restrict__ Cp,        // [512][6400] bf16
    float* __restrict__ Ca)                 // [32][6400] fp32
{
    __shared__ __align__(16) unsigned char smem[131072];
    const int t = threadIdx.x;
    // XCD swizzle: L = q*40 + mblk*8 + (nblk&7), nblk = q*8 + (nblk&7)
    const int L = blockIdx.x;
    int mblk, nblk;
    if (L >= 240) { const int i = L - 240; mblk = i >> 1; nblk = 48 + (i & 1); }
    else          { const int q = L / 40, r = L - q * 40;
                    mblk = r >> 3; nblk = q * 8 + (r & 7); }
    const int m0 = mblk * 128, n0 = nblk * 128;
    const int lane = t & 63, w = t >> 6;
    const int g = w >> 2, wq = w & 3;
    const int wm = wq >> 1, wn = wq & 1;
    const int row16 = lane & 15, quad = lane >> 4;

    f32x4 acc[4][4] = {};

    const unsigned short* gAbase = At + (((size_t)mblk * NKT) << 14);
    const unsigned short* gBbase = Bt + (((size_t)nblk * NKT) << 14);

    #define STAGE(kt, s)                                                      \
    {                                                                         \
        unsigned short* As_ = (unsigned short*)(smem + (s) * 65536);          \
        unsigned short* Bs_ = As_ + 16384;                                    \
        const unsigned short* ga = gAbase + ((size_t)(kt) << 14);             \
        const unsigned short* gb = gBbase + ((size_t)(kt) << 14);             \
        _Pragma("unroll")                                                     \
        for (int j = 0; j < 4; ++j) {                                         \
            async_copy16(ga + ((size_t)(j * 512 + t) << 3),                   \
                         As_ + ((size_t)(j * 512 + w * 64) << 3));            \
            async_copy16(gb + ((size_t)(j * 512 + t) << 3),                   \
                         Bs_ + ((size_t)(j * 512 + w * 64) << 3));            \
        }                                                                     \
    }

    #define COMPUTE(s)                                                        \
    {                                                                         \
        const unsigned short* As_ = (const unsigned short*)(smem + (s) * 65536);\
        const unsigned short* Bs_ = As_ + 16384;                              \
        _Pragma("unroll")                                                     \
        for (int ks = 0; ks < 2; ++ks) {                                      \
            const int kc8b = g * 8 + ks * 4 + quad;                           \
            const int sw = kc8b << 2;                                         \
            bf16x8 af[4], bfr[4];                                             \
            _Pragma("unroll")                                                 \
            for (int mt = 0; mt < 4; ++mt)                                    \
                af[mt] = *reinterpret_cast<const bf16x8*>(                    \
                    &As_[(size_t)(kc8b * 128 + ((wm * 64 + mt * 16 + row16) ^ sw)) * 8]);\
            _Pragma("unroll")                                                 \
            for (int nt = 0; nt < 4; ++nt)                                    \
                bfr[nt] = *reinterpret_cast<const bf16x8*>(                   \
                    &Bs_[(size_t)(kc8b * 128 + ((wn * 64 + nt * 16 + row16) ^ sw)) * 8]);\
            _Pragma("unroll")                                                 \
            for (int mt = 0; mt < 4; ++mt)                                    \
                _Pragma("unroll")                                             \
                for (int nt = 0; nt < 4; ++nt)                                \
                    acc[mt][nt] = __builtin_amdgcn_mfma_f32_16x16x32_bf16(    \
                        af[mt], bfr[nt], acc[mt][nt], 0, 0, 0);               \
        }                                                                     \
    }

    STAGE(0, 0);
    for (int kt = 0; kt < NKT; ++kt) {
        __syncthreads();
        if (kt + 1 < NKT) STAGE(kt + 1, (kt + 1) & 1);
        COMPUTE(kt & 1);
    }
    #undef STAGE
    #undef COMPUTE

    float* mb = (float*)smem;
    #pragma unroll
    for (int rnd = 0; rnd < 2; ++rnd) {
        __syncthreads();
        if (g == 1 && (wq >> 1) == rnd) {
            f32x4* dst = (f32x4*)(mb + (wq & 1) * 4096);
            #pragma unroll
            for (int i = 0; i < 16; ++i)
                dst[i * 64 + lane] = acc[i >> 2][i & 3];
        }
        __syncthreads();
        if (g == 0 && (wq >> 1) == rnd) {
            const f32x4* src = (const f32x4*)(mb + (wq & 1) * 4096);
            #pragma unroll
            for (int i = 0; i < 16; ++i)
                acc[i >> 2][i & 3] += src[i * 64 + lane];
        }
    }

    if (g == 0) {
        #pragma unroll
        for (int mt = 0; mt < 4; ++mt) {
            const int mbase = m0 + wm * 64 + mt * 16 + quad * 4;
            if (mbase >= 544) continue;
            #pragma unroll
            for (int rg = 0; rg < 4; ++rg) {
                const int m = mbase + rg;
                const float s = sc[m], bbx = bi[m];
                #pragma unroll
                for (int nt = 0; nt < 4; ++nt) {
                    const int n = n0 + wn * 64 + nt * 16 + row16;
                    const float v = fmaf(acc[mt][nt][rg], s, bbx);
                    if (m < 512) Cp[(size_t)m * NTOT + n] = f2bf(v);
                    else Ca[(size_t)(m - 512) * NTOT + n] = 1.f / (1.f + fexp(-v));
                }
            }
        }
    }
}

// ---------------------------------------------------------------------------
// EM routing (R7 shape, measured 85us / zero spills): 640 threads =
// 2 p-halves (rh) x 10 classes x 32 a-lanes, one block per batch.
// Only change vs R7: pose staged from bf16 Cp, activations from Ca.
// ---------------------------------------------------------------------------
__device__ __forceinline__ void loadW_bf(const unsigned short* wp, float* wv) {
    const int4* q = reinterpret_cast<const int4*>(wp);
    const int4 q0 = q[0], q1 = q[1];
    const unsigned int u[8] = {(unsigned)q0.x,(unsigned)q0.y,(unsigned)q0.z,(unsigned)q0.w,
                               (unsigned)q1.x,(unsigned)q1.y,(unsigned)q1.z,(unsigned)q1.w};
    #pragma unroll
    for (int i = 0; i < 8; ++i) {
        wv[2*i]   = __uint_as_float(u[i] << 16);
        wv[2*i+1] = __uint_as_float(u[i] & 0xFFFF0000u);
    }
}

__global__ __launch_bounds__(640, 1) void em_kernel(
    const unsigned short* __restrict__ Cp,    // [512][6400] bf16 pose
    const float* __restrict__ Ca,             // [32][6400] fp32 activations
    const unsigned short* __restrict__ Wmb,   // (800,10,16) bf16
    const float* __restrict__ beta_u, const float* __restrict__ beta_a,
    float* __restrict__ out)                  // (256,10)
{
    __shared__ __align__(16) float psh[25][32][20];   // 64 KB  pose [kk][a][16+pad]
    __shared__ float aush[800];
    __shared__ float lnqp[2][NCLS][800];              // 64 KB  partial ln_p; [1] reused as rw
    __shared__ float mu_sh[NCLS][16];
    __shared__ float i2s_sh[NCLS][16];
    __shared__ float costp[2][NCLS];
    __shared__ float slgp[2][NCLS];
    __shared__ float Kc_sh[NCLS];
    __shared__ float aout_sh[NCLS];

    const int b = blockIdx.x, t = threadIdx.x;
    const int rh = (t >= 320) ? 1 : 0;
    const int th = t - rh * 320;
    const int c = th >> 5, a = th & 31;
    float* rwsh = &lnqp[1][0][0];                     // aliases lnqp[1]

    // stage pose: Cp row c2 (0..511) -> psh[px][c2>>4][c2&15]
    const unsigned short* pb = Cp + (size_t)b * 25;
    for (int f = t; f < 12800; f += 640) {
        const int c2 = f / 25, px = f - c2 * 25;
        psh[px][c2 >> 4][c2 & 15] = bf2f(pb[(size_t)c2 * NTOT + px]);
    }
    const float* ab = Ca + (size_t)b * 25;
    for (int f = t; f < 800; f += 640) {
        const int ci = f / 25, px = f - ci * 25;
        aush[px * 32 + ci] = ab[(size_t)ci * NTOT + px];
    }
    __syncthreads();

    const float bu = beta_u[c], ba = beta_a[c];
    float muL[8], i2sL[8], KcL = 0.f;
    const unsigned short* wbase = Wmb + ((size_t)a * NCLS + c) * 16;  // + kk*5120

    #define VOTE_HALF(kk, vv)                                                \
        float pm[8], wv[16];                                                 \
        {                                                                    \
            const float4* pr = reinterpret_cast<const float4*>(&psh[kk][a][rh * 8]); \
            const float4 p0 = pr[0], p1 = pr[1];                             \
            pm[0]=p0.x; pm[1]=p0.y; pm[2]=p0.z; pm[3]=p0.w;                  \
            pm[4]=p1.x; pm[5]=p1.y; pm[6]=p1.z; pm[7]=p1.w;                  \
            loadW_bf(wbase + (size_t)(kk) * 5120, wv);                       \
            _Pragma("unroll")                                                \
            for (int jr = 0; jr < 2; ++jr) {                                 \
                _Pragma("unroll")                                            \
                for (int s = 0; s < 4; ++s) {                                \
                    float av = 0.f;                                          \
                    _Pragma("unroll")                                        \
                    for (int tt = 0; tt < 4; ++tt)                           \
                        av = fmaf(pm[jr*4+tt], wv[tt*4+s], av);              \
                    vv[jr*4+s] = av;                                         \
                }                                                            \
            }                                                                \
        }

    float p95 = 1.f;
    for (int it = 0; it < 3; ++it) {
        p95 *= 0.95f;
        const float lam = 0.01f * (1.f - p95);

        if (it > 0) {
            // ---- phase A: partial ln_p over this thread's 8 components ----
            for (int kk = 0; kk < 25; ++kk) {
                float vv[8];
                VOTE_HALF(kk, vv);
                float q = (rh == 0) ? KcL : 0.f;
                #pragma unroll
                for (int j = 0; j < 8; ++j) {
                    const float d = vv[j] - muL[j];
                    q -= d * d * i2sL[j];
                }
                lnqp[rh][c][kk * 32 + a] = q;
            }
            __syncthreads();
            // ---- phase M: merge halves into lnqp[0] ----
            {
                float* l0 = &lnqp[0][0][0];
                const float* l1 = &lnqp[1][0][0];
                for (int f = t; f < 8000; f += 640) l0[f] += l1[f];
            }
            __syncthreads();
            // ---- phase R: softmax over classes, once per (c,m) ----
            {
                const int k0 = rh ? 13 : 0, k1 = rh ? 25 : 13;
                for (int kk = k0; kk < k1; ++kk) {
                    const int m = kk * 32 + a;
                    float qv[NCLS];
                    #pragma unroll
                    for (int cc = 0; cc < NCLS; ++cc) qv[cc] = lnqp[0][cc][m];
                    float mx = qv[0];
                    #pragma unroll
                    for (int cc = 1; cc < NCLS; ++cc) mx = fmaxf(mx, qv[cc]);
                    float den = 0.f;
                    #pragma unroll
                    for (int cc = 0; cc < NCLS; ++cc) den += fexp(qv[cc] - mx);
                    rwsh[c * 800 + m] = fexp(qv[c] - mx) * __builtin_amdgcn_rcpf(den)
                                        * aush[m];
                }
            }
            __syncthreads();
        }

        // ---- phase S: weighted stats over this thread's 8 components ----
        float S0 = 0.f, S1[8], S2[8];
        #pragma unroll
        for (int j = 0; j < 8; ++j) { S1[j] = 0.f; S2[j] = 0.f; }

        for (int kk = 0; kk < 25; ++kk) {
            float vv[8];
            VOTE_HALF(kk, vv);
            const int m = kk * 32 + a;
            const float rw = (it == 0) ? aush[m] : rwsh[c * 800 + m];
            S0 += rw;
            #pragma unroll
            for (int j = 0; j < 8; ++j) {
                const float rv = rw * vv[j];
                S1[j] += rv;
                S2[j] = fmaf(rv, vv[j], S2[j]);
            }
        }

        // butterfly over the 32 a-lanes (within half-wave)
        #pragma unroll
        for (int off = 16; off >= 1; off >>= 1) {
            S0 += __shfl_xor(S0, off);
            #pragma unroll
            for (int j = 0; j < 8; ++j) {
                S1[j] += __shfl_xor(S1[j], off);
                S2[j] += __shfl_xor(S2[j], off);
            }
        }

        // per-half epilogue (both rh groups hold the SAME full S0)
        if (a == 0) {
            const float s0e = S0 + 1e-12f;
            const float inv = 1.f / s0e;
            float cost_ = 0.f, slg_ = 0.f;
            #pragma unroll
            for (int j = 0; j < 8; ++j) {
                const float mu_ = S1[j] * inv;
                const float sg = (S2[j] - 2.f * mu_ * S1[j] + mu_ * mu_ * S0) * inv
                                 + 1e-12f;
                cost_ += bu + 0.5f * flog(sg);
                slg_ += flog(sg * LN2PI_F);
                mu_sh[c][rh * 8 + j] = mu_;
                i2s_sh[c][rh * 8 + j] = 0.5f / sg;
            }
            costp[rh][c] = cost_;
            slgp[rh][c] = slg_;
        }
        __syncthreads();
        if (a == 0 && rh == 0) {
            const float costsum = (costp[0][c] + costp[1][c]) * S0;
            const float aout = 1.f / (1.f + fexp(-(lam * (ba - costsum))));
            aout_sh[c] = aout;
            Kc_sh[c] = flog(aout) - 0.5f * (slgp[0][c] + slgp[1][c]);
        }
        __syncthreads();
        if (it < 2) {
            #pragma unroll
            for (int j = 0; j < 8; ++j) {
                muL[j] = mu_sh[c][rh * 8 + j];
                i2sL[j] = i2s_sh[c][rh * 8 + j];
            }
            KcL = Kc_sh[c];
        }
    }

    if (t < NCLS) {
        float s = 0.f;
        #pragma unroll
        for (int cc = 0; cc < NCLS; ++cc) s += aout_sh[cc];
        out[b * NCLS + t] = flog(aout_sh[t] / s);
    }
    #undef VOTE_HALF
}

// ---------------------------------------------------------------------------
extern "C" void kernel_launch(void* const* d_in, const int* in_sizes, int n_in,
                              void* d_out, int out_size, void* d_ws, size_t ws_size,
                              hipStream_t stream) {
    const float* x      = (const float*)d_in[0];
    const float* w_a    = (const float*)d_in[1];
    const float* w_pose = (const float*)d_in[2];
    const float* bn_a_g = (const float*)d_in[3];
    const float* bn_a_b = (const float*)d_in[4];
    const float* bn_a_m = (const float*)d_in[5];
    const float* bn_a_v = (const float*)d_in[6];
    const float* bn_p_g = (const float*)d_in[7];
    const float* bn_p_b = (const float*)d_in[8];
    const float* bn_p_m = (const float*)d_in[9];
    const float* bn_p_v = (const float*)d_in[10];
    const float* Wm     = (const float*)d_in[11];
    const float* beta_u = (const float*)d_in[12];
    const float* beta_a = (const float*)d_in[13];
    float* out = (float*)d_out;

    char* p = (char*)d_ws;
    unsigned short* At  = (unsigned short*)p;  p += (size_t)MPAD * KDIM * 2;
    unsigned short* Bt  = (unsigned short*)p;  p += (size_t)NTOT * KDIM * 2;
    unsigned short* Wmb = (unsigned short*)p;  p += (size_t)800 * NCLS * 16 * 2;
    unsigned short* Cp  = (unsigned short*)p;  p += (size_t)512 * NTOT * 2;
    float* Ca = (float*)p;                     p += (size_t)32 * NTOT * 4;
    float* sc = (float*)p;                     p += MPAD * 4;
    float* bi = (float*)p;                     p += MPAD * 4;

    pack_a_kernel<<<NABLK + 63, 256, 0, stream>>>(w_pose, w_a,
                                                  bn_p_g, bn_p_b, bn_p_m, bn_p_v,
                                                  bn_a_g, bn_a_b, bn_a_m, bn_a_v,
                                                  Wm, At, Wmb, sc, bi);
    pack_b_kernel<<<256, 1024, 0, stream>>>(x, Bt);
    gemm_kernel<<<250, 512, 0, stream>>>(At, Bt, sc, bi, Cp, Ca);
    em_kernel<<<256, 640, 0, stream>>>(Cp, Ca, Wmb, beta_u, beta_a, out);
}

// Round 10
// 240.812 us; speedup vs baseline: 1.1300x; 1.0714x over previous
//
#include <hip/hip_runtime.h>
#include <math.h>

#define CIN 512
#define NCLS 10
#define KDIM 4608            // 512*9
#define NTOT 6400            // 256*25
#define MPAD 640
#define BK 128
#define NKT 36               // KDIM/BK
#define NABLK (5 * NKT)      // 180 A-tile blocks in pack_a
#define LN2PI_F 1.8378770664093453f

typedef __attribute__((ext_vector_type(8))) short bf16x8;
typedef __attribute__((ext_vector_type(4))) float f32x4;
typedef __attribute__((ext_vector_type(2))) float f32x2;

typedef const __attribute__((address_space(1))) void* gas_ptr;
typedef __attribute__((address_space(3))) void* las_ptr;

__device__ __forceinline__ void async_copy16(const void* g, void* l) {
    __builtin_amdgcn_global_load_lds((gas_ptr)g, (las_ptr)l, 16, 0, 0);
}

__device__ __forceinline__ unsigned short f2bf(float f) {
    unsigned int u = __float_as_uint(f);
    u = (u + 0x7fffu + ((u >> 16) & 1u)) >> 16;   // RNE
    return (unsigned short)u;
}
__device__ __forceinline__ float bf2f(unsigned short s) {
    return __uint_as_float(((unsigned int)s) << 16);
}
__device__ __forceinline__ float fexp(float x) { return __expf(x); }
__device__ __forceinline__ float flog(float x) { return __logf(x); }

// ---------------------------------------------------------------------------
// pack_a: blocks [0,180): weights fp32 -> bf16 pre-tiled for the GEMM's LDS
// staging order. Blocks [180, 243): Wm fp32 -> bf16 (for em_kernel).
// Block 0 additionally computes the folded BN scale/bias.
// ---------------------------------------------------------------------------
__global__ __launch_bounds__(256) void pack_a_kernel(
    const float* __restrict__ w_pose, const float* __restrict__ w_a,
    const float* __restrict__ bn_p_g, const float* __restrict__ bn_p_b,
    const float* __restrict__ bn_p_m, const float* __restrict__ bn_p_v,
    const float* __restrict__ bn_a_g, const float* __restrict__ bn_a_b,
    const float* __restrict__ bn_a_m, const float* __restrict__ bn_a_v,
    const float* __restrict__ Wm,
    unsigned short* __restrict__ At, unsigned short* __restrict__ Wmb,
    float* __restrict__ sc, float* __restrict__ bi)
{
    const int blk = blockIdx.x;
    const int t = threadIdx.x;

    if (blk >= NABLK) {                          // ---- Wm bf16 packing ----
        const int chunk = (blk - NABLK) * 256 + t;   // 8 floats per chunk
        if (chunk < 16000) {
            const float4* s4 = reinterpret_cast<const float4*>(Wm + (size_t)chunk * 8);
            float4 x0 = s4[0], x1 = s4[1];
            int4 o;
            o.x = (int)f2bf(x0.x) | ((int)f2bf(x0.y) << 16);
            o.y = (int)f2bf(x0.z) | ((int)f2bf(x0.w) << 16);
            o.z = (int)f2bf(x1.x) | ((int)f2bf(x1.y) << 16);
            o.w = (int)f2bf(x1.z) | ((int)f2bf(x1.w) << 16);
            reinterpret_cast<int4*>(Wmb + (size_t)chunk * 8)[0] = o;
        }
        return;
    }

    const int mblk = blk / NKT;
    if (blk == 0) {
        for (int i = t; i < MPAD; i += 256) {
            float s = 0.f, b = 0.f;
            if (i < 512) {
                s = bn_p_g[i] / sqrtf(bn_p_v[i] + 1e-5f);
                b = bn_p_b[i] - bn_p_m[i] * s;
            } else if (i < 544) {
                const int j = i - 512;
                s = bn_a_g[j] / sqrtf(bn_a_v[j] + 1e-5f);
                b = bn_a_b[j] - bn_a_m[j] * s;
            }
            sc[i] = s; bi[i] = b;
        }
    }

    const int kt = blk - mblk * NKT;
    #pragma unroll
    for (int j = 0; j < 8; ++j) {
        const int c = t + j * 256;               // 0..2047
        const int kc8 = c >> 7, slot = c & 127;
        const int row = mblk * 128 + (slot ^ (kc8 << 2));
        const int k0 = (kt * 16 + kc8) * 8;
        float v[8] = {0.f,0.f,0.f,0.f,0.f,0.f,0.f,0.f};
        if (row < 512) {
            const float4* s4 = reinterpret_cast<const float4*>(w_pose + (size_t)row * KDIM + k0);
            float4 x0 = s4[0], x1 = s4[1];
            v[0]=x0.x; v[1]=x0.y; v[2]=x0.z; v[3]=x0.w;
            v[4]=x1.x; v[5]=x1.y; v[6]=x1.z; v[7]=x1.w;
        } else if (row < 544) {
            const float4* s4 = reinterpret_cast<const float4*>(w_a + (size_t)(row - 512) * KDIM + k0);
            float4 x0 = s4[0], x1 = s4[1];
            v[0]=x0.x; v[1]=x0.y; v[2]=x0.z; v[3]=x0.w;
            v[4]=x1.x; v[5]=x1.y; v[6]=x1.z; v[7]=x1.w;
        }
        int4 o;
        o.x = (int)f2bf(v[0]) | ((int)f2bf(v[1]) << 16);
        o.y = (int)f2bf(v[2]) | ((int)f2bf(v[3]) << 16);
        o.z = (int)f2bf(v[4]) | ((int)f2bf(v[5]) << 16);
        o.w = (int)f2bf(v[6]) | ((int)f2bf(v[7]) << 16);
        reinterpret_cast<int4*>(At + ((((size_t)blk) << 11) + c) * 8)[0] = o;
    }
}

// ---------------------------------------------------------------------------
// pack_b: im2col fp32->bf16, pre-tiled. px-major work order: consecutive
// threads write consecutive c slots (25x16B = 400B runs) instead of 2KB
// scatter (R9's ch-major order caused ~4x write-sector amplification).
// ---------------------------------------------------------------------------
__global__ __launch_bounds__(1024) void pack_b_kernel(
    const float* __restrict__ x, unsigned short* __restrict__ Bt)
{
    __shared__ __align__(16) float xs[CIN * 25];
    const int b = blockIdx.x;
    const int t = threadIdx.x;
    const float4* xb = reinterpret_cast<const float4*>(x + (size_t)b * (CIN * 25));
    for (int f4 = t; f4 < (CIN * 25) / 4; f4 += 1024)
        reinterpret_cast<float4*>(xs)[f4] = xb[f4];
    __syncthreads();

    for (int w = t; w < 25 * (KDIM / 8); w += 1024) {
        const int ch = w / 25;                   // k-chunk (px-major order)
        const int px = w - ch * 25;
        const int py = px / 5, qx = px % 5;
        const int k0 = ch * 8;
        unsigned short v[8];
        #pragma unroll
        for (int j = 0; j < 8; ++j) {
            const int k = k0 + j;
            const int ci = k / 9;
            const int kk = k - ci * 9;
            const int dy = kk / 3, dx = kk - dy * 3;
            const int yy = py + dy - 1, xx = qx + dx - 1;
            const bool ok = (yy >= 0) & (yy < 5) & (xx >= 0) & (xx < 5);
            v[j] = ok ? f2bf(xs[ci * 25 + yy * 5 + xx]) : (unsigned short)0;
        }
        int4 o;
        o.x = (int)v[0] | ((int)v[1] << 16);
        o.y = (int)v[2] | ((int)v[3] << 16);
        o.z = (int)v[4] | ((int)v[5] << 16);
        o.w = (int)v[6] | ((int)v[7] << 16);
        const int n = b * 25 + px;
        const int nblk = n >> 7, nr = n & 127;
        const int kt = k0 >> 7;
        const int kc8 = (k0 >> 3) & 15;
        const int c = kc8 * 128 + (nr ^ (kc8 << 2));
        reinterpret_cast<int4*>(Bt + ((((size_t)(nblk * NKT + kt)) << 11) + c) * 8)[0] = o;
    }
}

// ---------------------------------------------------------------------------
// gemm: unchanged from R9 (XCD-swizzled 1-D grid, bf16 Cp / fp32 Ca split).
// ---------------------------------------------------------------------------
__global__ __launch_bounds__(512) void gemm_kernel(
    const unsigned short* __restrict__ At,
    const unsigned short* __restrict__ Bt,
    const float* __restrict__ sc, const float* __restrict__ bi,
    unsigned short* __restrict__ Cp,        // [512][6400] bf16
    float* __restrict__ Ca)                 // [32][6400] fp32
{
    __shared__ __align__(16) unsigned char smem[131072];
    const int t = threadIdx.x;
    const int L = blockIdx.x;
    int mblk, nblk;
    if (L >= 240) { const int i = L - 240; mblk = i >> 1; nblk = 48 + (i & 1); }
    else          { const int q = L / 40, r = L - q * 40;
                    mblk = r >> 3; nblk = q * 8 + (r & 7); }
    const int m0 = mblk * 128, n0 = nblk * 128;
    const int lane = t & 63, w = t >> 6;
    const int g = w >> 2, wq = w & 3;
    const int wm = wq >> 1, wn = wq & 1;
    const int row16 = lane & 15, quad = lane >> 4;

    f32x4 acc[4][4] = {};

    const unsigned short* gAbase = At + (((size_t)mblk * NKT) << 14);
    const unsigned short* gBbase = Bt + (((size_t)nblk * NKT) << 14);

    #define STAGE(kt, s)                                                      \
    {                                                                         \
        unsigned short* As_ = (unsigned short*)(smem + (s) * 65536);          \
        unsigned short* Bs_ = As_ + 16384;                                    \
        const unsigned short* ga = gAbase + ((size_t)(kt) << 14);             \
        const unsigned short* gb = gBbase + ((size_t)(kt) << 14);             \
        _Pragma("unroll")                                                     \
        for (int j = 0; j < 4; ++j) {                                         \
            async_copy16(ga + ((size_t)(j * 512 + t) << 3),                   \
                         As_ + ((size_t)(j * 512 + w * 64) << 3));            \
            async_copy16(gb + ((size_t)(j * 512 + t) << 3),                   \
                         Bs_ + ((size_t)(j * 512 + w * 64) << 3));            \
        }                                                                     \
    }

    #define COMPUTE(s)                                                        \
    {                                                                         \
        const unsigned short* As_ = (const unsigned short*)(smem + (s) * 65536);\
        const unsigned short* Bs_ = As_ + 16384;                              \
        _Pragma("unroll")                                                     \
        for (int ks = 0; ks < 2; ++ks) {                                      \
            const int kc8b = g * 8 + ks * 4 + quad;                           \
            const int sw = kc8b << 2;                                         \
            bf16x8 af[4], bfr[4];                                             \
            _Pragma("unroll")                                                 \
            for (int mt = 0; mt < 4; ++mt)                                    \
                af[mt] = *reinterpret_cast<const bf16x8*>(                    \
                    &As_[(size_t)(kc8b * 128 + ((wm * 64 + mt * 16 + row16) ^ sw)) * 8]);\
            _Pragma("unroll")                                                 \
            for (int nt = 0; nt < 4; ++nt)                                    \
                bfr[nt] = *reinterpret_cast<const bf16x8*>(                   \
                    &Bs_[(size_t)(kc8b * 128 + ((wn * 64 + nt * 16 + row16) ^ sw)) * 8]);\
            _Pragma("unroll")                                                 \
            for (int mt = 0; mt < 4; ++mt)                                    \
                _Pragma("unroll")                                             \
                for (int nt = 0; nt < 4; ++nt)                                \
                    acc[mt][nt] = __builtin_amdgcn_mfma_f32_16x16x32_bf16(    \
                        af[mt], bfr[nt], acc[mt][nt], 0, 0, 0);               \
        }                                                                     \
    }

    STAGE(0, 0);
    for (int kt = 0; kt < NKT; ++kt) {
        __syncthreads();
        if (kt + 1 < NKT) STAGE(kt + 1, (kt + 1) & 1);
        COMPUTE(kt & 1);
    }
    #undef STAGE
    #undef COMPUTE

    float* mb = (float*)smem;
    #pragma unroll
    for (int rnd = 0; rnd < 2; ++rnd) {
        __syncthreads();
        if (g == 1 && (wq >> 1) == rnd) {
            f32x4* dst = (f32x4*)(mb + (wq & 1) * 4096);
            #pragma unroll
            for (int i = 0; i < 16; ++i)
                dst[i * 64 + lane] = acc[i >> 2][i & 3];
        }
        __syncthreads();
        if (g == 0 && (wq >> 1) == rnd) {
            const f32x4* src = (const f32x4*)(mb + (wq & 1) * 4096);
            #pragma unroll
            for (int i = 0; i < 16; ++i)
                acc[i >> 2][i & 3] += src[i * 64 + lane];
        }
    }

    if (g == 0) {
        #pragma unroll
        for (int mt = 0; mt < 4; ++mt) {
            const int mbase = m0 + wm * 64 + mt * 16 + quad * 4;
            if (mbase >= 544) continue;
            #pragma unroll
            for (int rg = 0; rg < 4; ++rg) {
                const int m = mbase + rg;
                const float s = sc[m], bbx = bi[m];
                #pragma unroll
                for (int nt = 0; nt < 4; ++nt) {
                    const int n = n0 + wn * 64 + nt * 16 + row16;
                    const float v = fmaf(acc[mt][nt][rg], s, bbx);
                    if (m < 512) Cp[(size_t)m * NTOT + n] = f2bf(v);
                    else Ca[(size_t)(m - 512) * NTOT + n] = 1.f / (1.f + fexp(-v));
                }
            }
        }
    }
}

// ---------------------------------------------------------------------------
// EM routing (R7/R9 shape + packed-f32 math): 640 threads = 2 p-halves (rh)
// x 10 classes x 32 a-lanes, one block per batch. Vote/stats/ln_p computed
// as float2 vectors -> V_PK_FMA_F32 (2 fp32 FMA/inst). Phase S: W prefetch
// depth 2, pose/rw depth 1. Phase A: depth 1 (register budget).
// ---------------------------------------------------------------------------
__device__ __forceinline__ void unpackW2(const int4& q0, const int4& q1, f32x2* wv2) {
    const unsigned int u[8] = {(unsigned)q0.x,(unsigned)q0.y,(unsigned)q0.z,(unsigned)q0.w,
                               (unsigned)q1.x,(unsigned)q1.y,(unsigned)q1.z,(unsigned)q1.w};
    #pragma unroll
    for (int i = 0; i < 8; ++i) {
        f32x2 p;
        p.x = __uint_as_float(u[i] << 16);
        p.y = __uint_as_float(u[i] & 0xFFFF0000u);
        wv2[i] = p;   // = (W[i>>1][2*(i&1)], W[i>>1][2*(i&1)+1])
    }
}

// vote for p-half rh: v2[jp] = (v[2jp], v[2jp+1]), jp in [0,4)
__device__ __forceinline__ void vote_half2(const float* pm, const f32x2* wv2, f32x2* v2) {
    #pragma unroll
    for (int jr = 0; jr < 2; ++jr) {
        f32x2 vA = {0.f, 0.f}, vB = {0.f, 0.f};
        #pragma unroll
        for (int tt = 0; tt < 4; ++tt) {
            const f32x2 pb = {pm[jr*4+tt], pm[jr*4+tt]};
            vA += pb * wv2[tt*2+0];
            vB += pb * wv2[tt*2+1];
        }
        v2[jr*2+0] = vA;
        v2[jr*2+1] = vB;
    }
}

__global__ __launch_bounds__(640, 1) void em_kernel(
    const unsigned short* __restrict__ Cp,    // [512][6400] bf16 pose
    const float* __restrict__ Ca,             // [32][6400] fp32 activations
    const unsigned short* __restrict__ Wmb,   // (800,10,16) bf16
    const float* __restrict__ beta_u, const float* __restrict__ beta_a,
    float* __restrict__ out)                  // (256,10)
{
    __shared__ __align__(16) float psh[25][32][20];   // 64 KB  pose [kk][a][16+pad]
    __shared__ float aush[800];
    __shared__ float lnqp[2][NCLS][800];              // 64 KB  partial ln_p; [1] reused as rw
    __shared__ float mu_sh[NCLS][16];
    __shared__ float i2s_sh[NCLS][16];
    __shared__ float costp[2][NCLS];
    __shared__ float slgp[2][NCLS];
    __shared__ float Kc_sh[NCLS];
    __shared__ float aout_sh[NCLS];

    const int b = blockIdx.x, t = threadIdx.x;
    const int rh = (t >= 320) ? 1 : 0;
    const int th = t - rh * 320;
    const int c = th >> 5, a = th & 31;
    float* rwsh = &lnqp[1][0][0];                     // aliases lnqp[1]

    // stage pose: Cp row c2 (0..511) -> psh[px][c2>>4][c2&15]
    const unsigned short* pb = Cp + (size_t)b * 25;
    for (int f = t; f < 12800; f += 640) {
        const int c2 = f / 25, px = f - c2 * 25;
        psh[px][c2 >> 4][c2 & 15] = bf2f(pb[(size_t)c2 * NTOT + px]);
    }
    const float* ab = Ca + (size_t)b * 25;
    for (int f = t; f < 800; f += 640) {
        const int ci = f / 25, px = f - ci * 25;
        aush[px * 32 + ci] = ab[(size_t)ci * NTOT + px];
    }
    __syncthreads();

    const float bu = beta_u[c], ba = beta_a[c];
    f32x2 mu2[4], i2s2[4];
    float KcL = 0.f;
    const unsigned short* wbase = Wmb + ((size_t)a * NCLS + c) * 16;  // + kk*5120

    float p95 = 1.f;
    for (int it = 0; it < 3; ++it) {
        p95 *= 0.95f;
        const float lam = 0.01f * (1.f - p95);

        if (it > 0) {
            // ---- phase A: partial ln_p over this thread's 8 components ----
            int4 wr0 = *reinterpret_cast<const int4*>(wbase);
            int4 wr1 = *reinterpret_cast<const int4*>(wbase + 8);
            for (int kk = 0; kk < 25; ++kk) {
                const int4 w0 = wr0, w1 = wr1;
                if (kk < 24) {
                    const unsigned short* wn = wbase + (size_t)(kk + 1) * 5120;
                    wr0 = *reinterpret_cast<const int4*>(wn);
                    wr1 = *reinterpret_cast<const int4*>(wn + 8);
                }
                const float4* pr = reinterpret_cast<const float4*>(&psh[kk][a][rh * 8]);
                const float4 p0 = pr[0], p1 = pr[1];
                const float pm[8] = {p0.x,p0.y,p0.z,p0.w, p1.x,p1.y,p1.z,p1.w};
                f32x2 wv2[8], v2[4];
                unpackW2(w0, w1, wv2);
                vote_half2(pm, wv2, v2);
                f32x2 acc = {0.f, 0.f};
                #pragma unroll
                for (int jp = 0; jp < 4; ++jp) {
                    const f32x2 d = v2[jp] - mu2[jp];
                    acc += d * d * i2s2[jp];
                }
                lnqp[rh][c][kk * 32 + a] = ((rh == 0) ? KcL : 0.f) - acc.x - acc.y;
            }
            __syncthreads();
            // ---- phase M: merge halves into lnqp[0] ----
            {
                float* l0 = &lnqp[0][0][0];
                const float* l1 = &lnqp[1][0][0];
                for (int f = t; f < 8000; f += 640) l0[f] += l1[f];
            }
            __syncthreads();
            // ---- phase R: softmax over classes, once per (c,m) ----
            {
                const int k0 = rh ? 13 : 0, k1 = rh ? 25 : 13;
                for (int kk = k0; kk < k1; ++kk) {
                    const int m = kk * 32 + a;
                    float qv[NCLS];
                    #pragma unroll
                    for (int cc = 0; cc < NCLS; ++cc) qv[cc] = lnqp[0][cc][m];
                    float mx = qv[0];
                    #pragma unroll
                    for (int cc = 1; cc < NCLS; ++cc) mx = fmaxf(mx, qv[cc]);
                    float den = 0.f;
                    #pragma unroll
                    for (int cc = 0; cc < NCLS; ++cc) den += fexp(qv[cc] - mx);
                    rwsh[c * 800 + m] = fexp(qv[c] - mx) * __builtin_amdgcn_rcpf(den)
                                        * aush[m];
                }
            }
            __syncthreads();
        }

        // ---- phase S: weighted stats (W prefetch depth 2) ----
        const float* rwp = (it == 0) ? aush : &lnqp[1][0][0] + c * 800;
        float S0 = 0.f;
        f32x2 S1[4] = {}, S2[4] = {};

        int4 wA0 = *reinterpret_cast<const int4*>(wbase);
        int4 wA1 = *reinterpret_cast<const int4*>(wbase + 8);
        int4 wB0 = *reinterpret_cast<const int4*>(wbase + 5120);
        int4 wB1 = *reinterpret_cast<const int4*>(wbase + 5120 + 8);
        float4 pr0 = *reinterpret_cast<const float4*>(&psh[0][a][rh * 8]);
        float4 pr1 = *reinterpret_cast<const float4*>(&psh[0][a][rh * 8 + 4]);
        float rwC = rwp[a];
        for (int kk = 0; kk < 25; ++kk) {
            const int4 w0 = wA0, w1 = wA1;
            const float4 p0 = pr0, p1 = pr1;
            const float rw = rwC;
            const int k2 = (kk + 2 < 24) ? kk + 2 : 24;
            const int k1 = (kk + 1 < 24) ? kk + 1 : 24;
            wA0 = wB0; wA1 = wB1;
            {
                const unsigned short* wn = wbase + (size_t)k2 * 5120;
                wB0 = *reinterpret_cast<const int4*>(wn);
                wB1 = *reinterpret_cast<const int4*>(wn + 8);
            }
            pr0 = *reinterpret_cast<const float4*>(&psh[k1][a][rh * 8]);
            pr1 = *reinterpret_cast<const float4*>(&psh[k1][a][rh * 8 + 4]);
            rwC = rwp[k1 * 32 + a];

            const float pm[8] = {p0.x,p0.y,p0.z,p0.w, p1.x,p1.y,p1.z,p1.w};
            f32x2 wv2[8], v2[4];
            unpackW2(w0, w1, wv2);
            vote_half2(pm, wv2, v2);
            S0 += rw;
            const f32x2 rw2 = {rw, rw};
            #pragma unroll
            for (int jp = 0; jp < 4; ++jp) {
                const f32x2 rv = rw2 * v2[jp];
                S1[jp] += rv;
                S2[jp] += rv * v2[jp];
            }
        }

        // butterfly over the 32 a-lanes (within half-wave)
        float* S1f = reinterpret_cast<float*>(S1);
        float* S2f = reinterpret_cast<float*>(S2);
        #pragma unroll
        for (int off = 16; off >= 1; off >>= 1) {
            S0 += __shfl_xor(S0, off);
            #pragma unroll
            for (int j = 0; j < 8; ++j) {
                S1f[j] += __shfl_xor(S1f[j], off);
                S2f[j] += __shfl_xor(S2f[j], off);
            }
        }

        // per-half epilogue (both rh groups hold the SAME full S0)
        if (a == 0) {
            const float s0e = S0 + 1e-12f;
            const float inv = 1.f / s0e;
            float cost_ = 0.f, slg_ = 0.f;
            #pragma unroll
            for (int j = 0; j < 8; ++j) {
                const float mu_ = S1f[j] * inv;
                const float sg = (S2f[j] - 2.f * mu_ * S1f[j] + mu_ * mu_ * S0) * inv
                                 + 1e-12f;
                cost_ += bu + 0.5f * flog(sg);
                slg_ += flog(sg * LN2PI_F);
                mu_sh[c][rh * 8 + j] = mu_;
                i2s_sh[c][rh * 8 + j] = 0.5f / sg;
            }
            costp[rh][c] = cost_;
            slgp[rh][c] = slg_;
        }
        __syncthreads();
        if (a == 0 && rh == 0) {
            const float costsum = (costp[0][c] + costp[1][c]) * S0;
            const float aout = 1.f / (1.f + fexp(-(lam * (ba - costsum))));
            aout_sh[c] = aout;
            Kc_sh[c] = flog(aout) - 0.5f * (slgp[0][c] + slgp[1][c]);
        }
        __syncthreads();
        if (it < 2) {
            #pragma unroll
            for (int jp = 0; jp < 4; ++jp) {
                f32x2 m2, s2;
                m2.x = mu_sh[c][rh * 8 + jp * 2];
                m2.y = mu_sh[c][rh * 8 + jp * 2 + 1];
                s2.x = i2s_sh[c][rh * 8 + jp * 2];
                s2.y = i2s_sh[c][rh * 8 + jp * 2 + 1];
                mu2[jp] = m2; i2s2[jp] = s2;
            }
            KcL = Kc_sh[c];
        }
    }

    if (t < NCLS) {
        float s = 0.f;
        #pragma unroll
        for (int cc = 0; cc < NCLS; ++cc) s += aout_sh[cc];
        out[b * NCLS + t] = flog(aout_sh[t] / s);
    }
}

// ---------------------------------------------------------------------------
extern "C" void kernel_launch(void* const* d_in, const int* in_sizes, int n_in,
                              void* d_out, int out_size, void* d_ws, size_t ws_size,
                              hipStream_t stream) {
    const float* x      = (const float*)d_in[0];
    const float* w_a    = (const float*)d_in[1];
    const float* w_pose = (const float*)d_in[2];
    const float* bn_a_g = (const float*)d_in[3];
    const float* bn_a_b = (const float*)d_in[4];
    const float* bn_a_m = (const float*)d_in[5];
    const float* bn_a_v = (const float*)d_in[6];
    const float* bn_p_g = (const float*)d_in[7];
    const float* bn_p_b = (const float*)d_in[8];
    const float* bn_p_m = (const float*)d_in[9];
    const float* bn_p_v = (const float*)d_in[10];
    const float* Wm     = (const float*)d_in[11];
    const float* beta_u = (const float*)d_in[12];
    const float* beta_a = (const float*)d_in[13];
    float* out = (float*)d_out;

    char* p = (char*)d_ws;
    unsigned short* At  = (unsigned short*)p;  p += (size_t)MPAD * KDIM * 2;
    unsigned short* Bt  = (unsigned short*)p;  p += (size_t)NTOT * KDIM * 2;
    unsigned short* Wmb = (unsigned short*)p;  p += (size_t)800 * NCLS * 16 * 2;
    unsigned short* Cp  = (unsigned short*)p;  p += (size_t)512 * NTOT * 2;
    float* Ca = (float*)p;                     p += (size_t)32 * NTOT * 4;
    float* sc = (float*)p;                     p += MPAD * 4;
    float* bi = (float*)p;                     p += MPAD * 4;

    pack_a_kernel<<<NABLK + 63, 256, 0, stream>>>(w_pose, w_a,
                                                  bn_p_g, bn_p_b, bn_p_m, bn_p_v,
                                                  bn_a_g, bn_a_b, bn_a_m, bn_a_v,
                                                  Wm, At, Wmb, sc, bi);
    pack_b_kernel<<<256, 1024, 0, stream>>>(x, Bt);
    gemm_kernel<<<250, 512, 0, stream>>>(At, Bt, sc, bi, Cp, Ca);
    em_kernel<<<256, 640, 0, stream>>>(Cp, Ca, Wmb, beta_u, beta_a, out);
}

// Round 11
// 238.473 us; speedup vs baseline: 1.1411x; 1.0098x over previous
//
#include <hip/hip_runtime.h>
#include <math.h>

#define CIN 512
#define NCLS 10
#define KDIM 4608            // 512*9
#define NTOT 6400            // 256*25
#define MPAD 640
#define BK 128
#define NKT 36               // KDIM/BK
#define NABLK (5 * NKT)      // 180 A-tile blocks in pack_a
#define LN2PI_F 1.8378770664093453f

typedef __attribute__((ext_vector_type(8))) short bf16x8;
typedef __attribute__((ext_vector_type(4))) float f32x4;

typedef const __attribute__((address_space(1))) void* gas_ptr;
typedef __attribute__((address_space(3))) void* las_ptr;

__device__ __forceinline__ void async_copy16(const void* g, void* l) {
    __builtin_amdgcn_global_load_lds((gas_ptr)g, (las_ptr)l, 16, 0, 0);
}

__device__ __forceinline__ unsigned short f2bf(float f) {
    unsigned int u = __float_as_uint(f);
    u = (u + 0x7fffu + ((u >> 16) & 1u)) >> 16;   // RNE
    return (unsigned short)u;
}
__device__ __forceinline__ float bf2f(unsigned short s) {
    return __uint_as_float(((unsigned int)s) << 16);
}
__device__ __forceinline__ float fexp(float x) { return __expf(x); }
__device__ __forceinline__ float flog(float x) { return __logf(x); }

// ---------------------------------------------------------------------------
// pack_a: blocks [0,180): weights fp32 -> bf16 pre-tiled for the GEMM's LDS
// staging order. Blocks [180, 243): Wm fp32 -> bf16 (for em_kernel).
// Block 0 additionally computes the folded BN scale/bias.
// ---------------------------------------------------------------------------
__global__ __launch_bounds__(256) void pack_a_kernel(
    const float* __restrict__ w_pose, const float* __restrict__ w_a,
    const float* __restrict__ bn_p_g, const float* __restrict__ bn_p_b,
    const float* __restrict__ bn_p_m, const float* __restrict__ bn_p_v,
    const float* __restrict__ bn_a_g, const float* __restrict__ bn_a_b,
    const float* __restrict__ bn_a_m, const float* __restrict__ bn_a_v,
    const float* __restrict__ Wm,
    unsigned short* __restrict__ At, unsigned short* __restrict__ Wmb,
    float* __restrict__ sc, float* __restrict__ bi)
{
    const int blk = blockIdx.x;
    const int t = threadIdx.x;

    if (blk >= NABLK) {                          // ---- Wm bf16 packing ----
        const int chunk = (blk - NABLK) * 256 + t;   // 8 floats per chunk
        if (chunk < 16000) {
            const float4* s4 = reinterpret_cast<const float4*>(Wm + (size_t)chunk * 8);
            float4 x0 = s4[0], x1 = s4[1];
            int4 o;
            o.x = (int)f2bf(x0.x) | ((int)f2bf(x0.y) << 16);
            o.y = (int)f2bf(x0.z) | ((int)f2bf(x0.w) << 16);
            o.z = (int)f2bf(x1.x) | ((int)f2bf(x1.y) << 16);
            o.w = (int)f2bf(x1.z) | ((int)f2bf(x1.w) << 16);
            reinterpret_cast<int4*>(Wmb + (size_t)chunk * 8)[0] = o;
        }
        return;
    }

    const int mblk = blk / NKT;
    if (blk == 0) {
        for (int i = t; i < MPAD; i += 256) {
            float s = 0.f, b = 0.f;
            if (i < 512) {
                s = bn_p_g[i] / sqrtf(bn_p_v[i] + 1e-5f);
                b = bn_p_b[i] - bn_p_m[i] * s;
            } else if (i < 544) {
                const int j = i - 512;
                s = bn_a_g[j] / sqrtf(bn_a_v[j] + 1e-5f);
                b = bn_a_b[j] - bn_a_m[j] * s;
            }
            sc[i] = s; bi[i] = b;
        }
    }

    const int kt = blk - mblk * NKT;
    #pragma unroll
    for (int j = 0; j < 8; ++j) {
        const int c = t + j * 256;               // 0..2047
        const int kc8 = c >> 7, slot = c & 127;
        const int row = mblk * 128 + (slot ^ (kc8 << 2));
        const int k0 = (kt * 16 + kc8) * 8;
        float v[8] = {0.f,0.f,0.f,0.f,0.f,0.f,0.f,0.f};
        if (row < 512) {
            const float4* s4 = reinterpret_cast<const float4*>(w_pose + (size_t)row * KDIM + k0);
            float4 x0 = s4[0], x1 = s4[1];
            v[0]=x0.x; v[1]=x0.y; v[2]=x0.z; v[3]=x0.w;
            v[4]=x1.x; v[5]=x1.y; v[6]=x1.z; v[7]=x1.w;
        } else if (row < 544) {
            const float4* s4 = reinterpret_cast<const float4*>(w_a + (size_t)(row - 512) * KDIM + k0);
            float4 x0 = s4[0], x1 = s4[1];
            v[0]=x0.x; v[1]=x0.y; v[2]=x0.z; v[3]=x0.w;
            v[4]=x1.x; v[5]=x1.y; v[6]=x1.z; v[7]=x1.w;
        }
        int4 o;
        o.x = (int)f2bf(v[0]) | ((int)f2bf(v[1]) << 16);
        o.y = (int)f2bf(v[2]) | ((int)f2bf(v[3]) << 16);
        o.z = (int)f2bf(v[4]) | ((int)f2bf(v[5]) << 16);
        o.w = (int)f2bf(v[6]) | ((int)f2bf(v[7]) << 16);
        reinterpret_cast<int4*>(At + ((((size_t)blk) << 11) + c) * 8)[0] = o;
    }
}

// ---------------------------------------------------------------------------
// pack_b: im2col fp32->bf16, pre-tiled, px-major work order (R10 win:
// consecutive threads write consecutive 16B slots -> 400B runs).
// ---------------------------------------------------------------------------
__global__ __launch_bounds__(1024) void pack_b_kernel(
    const float* __restrict__ x, unsigned short* __restrict__ Bt)
{
    __shared__ __align__(16) float xs[CIN * 25];
    const int b = blockIdx.x;
    const int t = threadIdx.x;
    const float4* xb = reinterpret_cast<const float4*>(x + (size_t)b * (CIN * 25));
    for (int f4 = t; f4 < (CIN * 25) / 4; f4 += 1024)
        reinterpret_cast<float4*>(xs)[f4] = xb[f4];
    __syncthreads();

    for (int w = t; w < 25 * (KDIM / 8); w += 1024) {
        const int ch = w / 25;                   // k-chunk (px-major order)
        const int px = w - ch * 25;
        const int py = px / 5, qx = px % 5;
        const int k0 = ch * 8;
        unsigned short v[8];
        #pragma unroll
        for (int j = 0; j < 8; ++j) {
            const int k = k0 + j;
            const int ci = k / 9;
            const int kk = k - ci * 9;
            const int dy = kk / 3, dx = kk - dy * 3;
            const int yy = py + dy - 1, xx = qx + dx - 1;
            const bool ok = (yy >= 0) & (yy < 5) & (xx >= 0) & (xx < 5);
            v[j] = ok ? f2bf(xs[ci * 25 + yy * 5 + xx]) : (unsigned short)0;
        }
        int4 o;
        o.x = (int)v[0] | ((int)v[1] << 16);
        o.y = (int)v[2] | ((int)v[3] << 16);
        o.z = (int)v[4] | ((int)v[5] << 16);
        o.w = (int)v[6] | ((int)v[7] << 16);
        const int n = b * 25 + px;
        const int nblk = n >> 7, nr = n & 127;
        const int kt = k0 >> 7;
        const int kc8 = (k0 >> 3) & 15;
        const int c = kc8 * 128 + (nr ^ (kc8 << 2));
        reinterpret_cast<int4*>(Bt + ((((size_t)(nblk * NKT + kt)) << 11) + c) * 8)[0] = o;
    }
}

// ---------------------------------------------------------------------------
// gemm v2: 1024 threads = 16 waves = 4 K-groups x (2m x 2n), wave tile
// 64x64, 128x128 block tile, BK=128 double-buffered (128 KB LDS).
// 4 waves/SIMD (was 2): deeper wave-level overlap of ds_read/MFMA chains
// between the per-iteration barrier drains. 3-round LDS merge of K-groups.
// ---------------------------------------------------------------------------
__global__ __launch_bounds__(1024) void gemm_kernel(
    const unsigned short* __restrict__ At,
    const unsigned short* __restrict__ Bt,
    const float* __restrict__ sc, const float* __restrict__ bi,
    unsigned short* __restrict__ Cp,        // [512][6400] bf16
    float* __restrict__ Ca)                 // [32][6400] fp32
{
    __shared__ __align__(16) unsigned char smem[131072];
    const int t = threadIdx.x;
    const int L = blockIdx.x;
    int mblk, nblk;
    if (L >= 240) { const int i = L - 240; mblk = i >> 1; nblk = 48 + (i & 1); }
    else          { const int q = L / 40, r = L - q * 40;
                    mblk = r >> 3; nblk = q * 8 + (r & 7); }
    const int m0 = mblk * 128, n0 = nblk * 128;
    const int lane = t & 63, w = t >> 6;
    const int g = w >> 2, wq = w & 3;          // 4 K-groups x 4 tile-waves
    const int wm = wq >> 1, wn = wq & 1;
    const int row16 = lane & 15, quad = lane >> 4;

    f32x4 acc[4][4] = {};

    const unsigned short* gAbase = At + (((size_t)mblk * NKT) << 14);
    const unsigned short* gBbase = Bt + (((size_t)nblk * NKT) << 14);

    #define STAGE(kt, s)                                                      \
    {                                                                         \
        unsigned short* As_ = (unsigned short*)(smem + (s) * 65536);          \
        unsigned short* Bs_ = As_ + 16384;                                    \
        const unsigned short* ga = gAbase + ((size_t)(kt) << 14);             \
        const unsigned short* gb = gBbase + ((size_t)(kt) << 14);             \
        _Pragma("unroll")                                                     \
        for (int j = 0; j < 2; ++j) {                                         \
            async_copy16(ga + ((size_t)(j * 1024 + t) << 3),                  \
                         As_ + ((size_t)(j * 1024 + w * 64) << 3));           \
            async_copy16(gb + ((size_t)(j * 1024 + t) << 3),                  \
                         Bs_ + ((size_t)(j * 1024 + w * 64) << 3));           \
        }                                                                     \
    }

    #define COMPUTE(s)                                                        \
    {                                                                         \
        const unsigned short* As_ = (const unsigned short*)(smem + (s) * 65536);\
        const unsigned short* Bs_ = As_ + 16384;                              \
        const int kc8b = g * 4 + quad;                                        \
        const int sw = kc8b << 2;                                             \
        bf16x8 af[4], bfr[4];                                                 \
        _Pragma("unroll")                                                     \
        for (int mt = 0; mt < 4; ++mt)                                        \
            af[mt] = *reinterpret_cast<const bf16x8*>(                        \
                &As_[(size_t)(kc8b * 128 + ((wm * 64 + mt * 16 + row16) ^ sw)) * 8]);\
        _Pragma("unroll")                                                     \
        for (int nt = 0; nt < 4; ++nt)                                        \
            bfr[nt] = *reinterpret_cast<const bf16x8*>(                       \
                &Bs_[(size_t)(kc8b * 128 + ((wn * 64 + nt * 16 + row16) ^ sw)) * 8]);\
        _Pragma("unroll")                                                     \
        for (int mt = 0; mt < 4; ++mt)                                        \
            _Pragma("unroll")                                                 \
            for (int nt = 0; nt < 4; ++nt)                                    \
                acc[mt][nt] = __builtin_amdgcn_mfma_f32_16x16x32_bf16(        \
                    af[mt], bfr[nt], acc[mt][nt], 0, 0, 0);                   \
    }

    STAGE(0, 0);
    for (int kt = 0; kt < NKT; ++kt) {
        __syncthreads();
        if (kt + 1 < NKT) STAGE(kt + 1, (kt + 1) & 1);
        COMPUTE(kt & 1);
    }
    #undef STAGE
    #undef COMPUTE

    // merge the 4 K-groups into group 0 (3 rounds through 64 KB of LDS)
    f32x4* mb = (f32x4*)smem;                 // 4096 f32x4 slots
    #pragma unroll
    for (int r = 1; r < 4; ++r) {
        __syncthreads();
        if (g == r) {
            f32x4* dst = mb + wq * 1024;
            #pragma unroll
            for (int i = 0; i < 16; ++i)
                dst[i * 64 + lane] = acc[i >> 2][i & 3];
        }
        __syncthreads();
        if (g == 0) {
            const f32x4* src = mb + wq * 1024;
            #pragma unroll
            for (int i = 0; i < 16; ++i)
                acc[i >> 2][i & 3] += src[i * 64 + lane];
        }
    }

    if (g == 0) {
        #pragma unroll
        for (int mt = 0; mt < 4; ++mt) {
            const int mbase = m0 + wm * 64 + mt * 16 + quad * 4;
            if (mbase >= 544) continue;
            #pragma unroll
            for (int rg = 0; rg < 4; ++rg) {
                const int m = mbase + rg;
                const float s = sc[m], bbx = bi[m];
                #pragma unroll
                for (int nt = 0; nt < 4; ++nt) {
                    const int n = n0 + wn * 64 + nt * 16 + row16;
                    const float v = fmaf(acc[mt][nt][rg], s, bbx);
                    if (m < 512) Cp[(size_t)m * NTOT + n] = f2bf(v);
                    else Ca[(size_t)(m - 512) * NTOT + n] = 1.f / (1.f + fexp(-v));
                }
            }
        }
    }
}

// ---------------------------------------------------------------------------
// EM routing — R9 code verbatim (measured 84 us, 72 VGPR, zero spills).
// 640 threads = 2 p-halves (rh) x 10 classes x 32 a-lanes, 1 block/batch.
// ---------------------------------------------------------------------------
__device__ __forceinline__ void loadW_bf(const unsigned short* wp, float* wv) {
    const int4* q = reinterpret_cast<const int4*>(wp);
    const int4 q0 = q[0], q1 = q[1];
    const unsigned int u[8] = {(unsigned)q0.x,(unsigned)q0.y,(unsigned)q0.z,(unsigned)q0.w,
                               (unsigned)q1.x,(unsigned)q1.y,(unsigned)q1.z,(unsigned)q1.w};
    #pragma unroll
    for (int i = 0; i < 8; ++i) {
        wv[2*i]   = __uint_as_float(u[i] << 16);
        wv[2*i+1] = __uint_as_float(u[i] & 0xFFFF0000u);
    }
}

__global__ __launch_bounds__(640, 1) void em_kernel(
    const unsigned short* __restrict__ Cp,    // [512][6400] bf16 pose
    const float* __restrict__ Ca,             // [32][6400] fp32 activations
    const unsigned short* __restrict__ Wmb,   // (800,10,16) bf16
    const float* __restrict__ beta_u, const float* __restrict__ beta_a,
    float* __restrict__ out)                  // (256,10)
{
    __shared__ __align__(16) float psh[25][32][20];   // 64 KB  pose [kk][a][16+pad]
    __shared__ float aush[800];
    __shared__ float lnqp[2][NCLS][800];              // 64 KB  partial ln_p; [1] reused as rw
    __shared__ float mu_sh[NCLS][16];
    __shared__ float i2s_sh[NCLS][16];
    __shared__ float costp[2][NCLS];
    __shared__ float slgp[2][NCLS];
    __shared__ float Kc_sh[NCLS];
    __shared__ float aout_sh[NCLS];

    const int b = blockIdx.x, t = threadIdx.x;
    const int rh = (t >= 320) ? 1 : 0;
    const int th = t - rh * 320;
    const int c = th >> 5, a = th & 31;
    float* rwsh = &lnqp[1][0][0];                     // aliases lnqp[1]

    // stage pose: Cp row c2 (0..511) -> psh[px][c2>>4][c2&15]
    const unsigned short* pb = Cp + (size_t)b * 25;
    for (int f = t; f < 12800; f += 640) {
        const int c2 = f / 25, px = f - c2 * 25;
        psh[px][c2 >> 4][c2 & 15] = bf2f(pb[(size_t)c2 * NTOT + px]);
    }
    const float* ab = Ca + (size_t)b * 25;
    for (int f = t; f < 800; f += 640) {
        const int ci = f / 25, px = f - ci * 25;
        aush[px * 32 + ci] = ab[(size_t)ci * NTOT + px];
    }
    __syncthreads();

    const float bu = beta_u[c], ba = beta_a[c];
    float muL[8], i2sL[8], KcL = 0.f;
    const unsigned short* wbase = Wmb + ((size_t)a * NCLS + c) * 16;  // + kk*5120

    #define VOTE_HALF(kk, vv)                                                \
        float pm[8], wv[16];                                                 \
        {                                                                    \
            const float4* pr = reinterpret_cast<const float4*>(&psh[kk][a][rh * 8]); \
            const float4 p0 = pr[0], p1 = pr[1];                             \
            pm[0]=p0.x; pm[1]=p0.y; pm[2]=p0.z; pm[3]=p0.w;                  \
            pm[4]=p1.x; pm[5]=p1.y; pm[6]=p1.z; pm[7]=p1.w;                  \
            loadW_bf(wbase + (size_t)(kk) * 5120, wv);                       \
            _Pragma("unroll")                                                \
            for (int jr = 0; jr < 2; ++jr) {                                 \
                _Pragma("unroll")                                            \
                for (int s = 0; s < 4; ++s) {                                \
                    float av = 0.f;                                          \
                    _Pragma("unroll")                                        \
                    for (int tt = 0; tt < 4; ++tt)                           \
                        av = fmaf(pm[jr*4+tt], wv[tt*4+s], av);              \
                    vv[jr*4+s] = av;                                         \
                }                                                            \
            }                                                                \
        }

    float p95 = 1.f;
    for (int it = 0; it < 3; ++it) {
        p95 *= 0.95f;
        const float lam = 0.01f * (1.f - p95);

        if (it > 0) {
            // ---- phase A: partial ln_p over this thread's 8 components ----
            for (int kk = 0; kk < 25; ++kk) {
                float vv[8];
                VOTE_HALF(kk, vv);
                float q = (rh == 0) ? KcL : 0.f;
                #pragma unroll
                for (int j = 0; j < 8; ++j) {
                    const float d = vv[j] - muL[j];
                    q -= d * d * i2sL[j];
                }
                lnqp[rh][c][kk * 32 + a] = q;
            }
            __syncthreads();
            // ---- phase M: merge halves into lnqp[0] ----
            {
                float* l0 = &lnqp[0][0][0];
                const float* l1 = &lnqp[1][0][0];
                for (int f = t; f < 8000; f += 640) l0[f] += l1[f];
            }
            __syncthreads();
            // ---- phase R: softmax over classes, once per (c,m) ----
            {
                const int k0 = rh ? 13 : 0, k1 = rh ? 25 : 13;
                for (int kk = k0; kk < k1; ++kk) {
                    const int m = kk * 32 + a;
                    float qv[NCLS];
                    #pragma unroll
                    for (int cc = 0; cc < NCLS; ++cc) qv[cc] = lnqp[0][cc][m];
                    float mx = qv[0];
                    #pragma unroll
                    for (int cc = 1; cc < NCLS; ++cc) mx = fmaxf(mx, qv[cc]);
                    float den = 0.f;
                    #pragma unroll
                    for (int cc = 0; cc < NCLS; ++cc) den += fexp(qv[cc] - mx);
                    rwsh[c * 800 + m] = fexp(qv[c] - mx) * __builtin_amdgcn_rcpf(den)
                                        * aush[m];
                }
            }
            __syncthreads();
        }

        // ---- phase S: weighted stats over this thread's 8 components ----
        float S0 = 0.f, S1[8], S2[8];
        #pragma unroll
        for (int j = 0; j < 8; ++j) { S1[j] = 0.f; S2[j] = 0.f; }

        for (int kk = 0; kk < 25; ++kk) {
            float vv[8];
            VOTE_HALF(kk, vv);
            const int m = kk * 32 + a;
            const float rw = (it == 0) ? aush[m] : rwsh[c * 800 + m];
            S0 += rw;
            #pragma unroll
            for (int j = 0; j < 8; ++j) {
                const float rv = rw * vv[j];
                S1[j] += rv;
                S2[j] = fmaf(rv, vv[j], S2[j]);
            }
        }

        // butterfly over the 32 a-lanes (within half-wave)
        #pragma unroll
        for (int off = 16; off >= 1; off >>= 1) {
            S0 += __shfl_xor(S0, off);
            #pragma unroll
            for (int j = 0; j < 8; ++j) {
                S1[j] += __shfl_xor(S1[j], off);
                S2[j] += __shfl_xor(S2[j], off);
            }
        }

        // per-half epilogue (both rh groups hold the SAME full S0)
        if (a == 0) {
            const float s0e = S0 + 1e-12f;
            const float inv = 1.f / s0e;
            float cost_ = 0.f, slg_ = 0.f;
            #pragma unroll
            for (int j = 0; j < 8; ++j) {
                const float mu_ = S1[j] * inv;
                const float sg = (S2[j] - 2.f * mu_ * S1[j] + mu_ * mu_ * S0) * inv
                                 + 1e-12f;
                cost_ += bu + 0.5f * flog(sg);
                slg_ += flog(sg * LN2PI_F);
                mu_sh[c][rh * 8 + j] = mu_;
                i2s_sh[c][rh * 8 + j] = 0.5f / sg;
            }
            costp[rh][c] = cost_;
            slgp[rh][c] = slg_;
        }
        __syncthreads();
        if (a == 0 && rh == 0) {
            const float costsum = (costp[0][c] + costp[1][c]) * S0;
            const float aout = 1.f / (1.f + fexp(-(lam * (ba - costsum))));
            aout_sh[c] = aout;
            Kc_sh[c] = flog(aout) - 0.5f * (slgp[0][c] + slgp[1][c]);
        }
        __syncthreads();
        if (it < 2) {
            #pragma unroll
            for (int j = 0; j < 8; ++j) {
                muL[j] = mu_sh[c][rh * 8 + j];
                i2sL[j] = i2s_sh[c][rh * 8 + j];
            }
            KcL = Kc_sh[c];
        }
    }

    if (t < NCLS) {
        float s = 0.f;
        #pragma unroll
        for (int cc = 0; cc < NCLS; ++cc) s += aout_sh[cc];
        out[b * NCLS + t] = flog(aout_sh[t] / s);
    }
    #undef VOTE_HALF
}

// ---------------------------------------------------------------------------
extern "C" void kernel_launch(void* const* d_in, const int* in_sizes, int n_in,
                              void* d_out, int out_size, void* d_ws, size_t ws_size,
                              hipStream_t stream) {
    const float* x      = (const float*)d_in[0];
    const float* w_a    = (const float*)d_in[1];
    const float* w_pose = (const float*)d_in[2];
    const float* bn_a_g = (const float*)d_in[3];
    const float* bn_a_b = (const float*)d_in[4];
    const float* bn_a_m = (const float*)d_in[5];
    const float* bn_a_v = (const float*)d_in[6];
    const float* bn_p_g = (const float*)d_in[7];
    const float* bn_p_b = (const float*)d_in[8];
    const float* bn_p_m = (const float*)d_in[9];
    const float* bn_p_v = (const float*)d_in[10];
    const float* Wm     = (const float*)d_in[11];
    const float* beta_u = (const float*)d_in[12];
    const float* beta_a = (const float*)d_in[13];
    float* out = (float*)d_out;

    char* p = (char*)d_ws;
    unsigned short* At  = (unsigned short*)p;  p += (size_t)MPAD * KDIM * 2;
    unsigned short* Bt  = (unsigned short*)p;  p += (size_t)NTOT * KDIM * 2;
    unsigned short* Wmb = (unsigned short*)p;  p += (size_t)800 * NCLS * 16 * 2;
    unsigned short* Cp  = (unsigned short*)p;  p += (size_t)512 * NTOT * 2;
    float* Ca = (float*)p;                     p += (size_t)32 * NTOT * 4;
    float* sc = (float*)p;                     p += MPAD * 4;
    float* bi = (float*)p;                     p += MPAD * 4;

    pack_a_kernel<<<NABLK + 63, 256, 0, stream>>>(w_pose, w_a,
                                                  bn_p_g, bn_p_b, bn_p_m, bn_p_v,
                                                  bn_a_g, bn_a_b, bn_a_m, bn_a_v,
                                                  Wm, At, Wmb, sc, bi);
    pack_b_kernel<<<256, 1024, 0, stream>>>(x, Bt);
    gemm_kernel<<<250, 1024, 0, stream>>>(At, Bt, sc, bi, Cp, Ca);
    em_kernel<<<256, 640, 0, stream>>>(Cp, Ca, Wmb, beta_u, beta_a, out);
}

// Round 12
// 232.537 us; speedup vs baseline: 1.1703x; 1.0255x over previous
//
#include <hip/hip_runtime.h>
#include <math.h>

#define CIN 512
#define NCLS 10
#define KDIM 4608            // 512*9
#define NTOT 6400            // 256*25
#define MPAD 640
#define BK 128
#define NKT 36               // KDIM/BK
#define NABLK (5 * NKT)      // 180 A-tile blocks in pack_a
#define LN2PI_F 1.8378770664093453f

typedef __attribute__((ext_vector_type(8))) short bf16x8;
typedef __attribute__((ext_vector_type(4))) float f32x4;

typedef const __attribute__((address_space(1))) void* gas_ptr;
typedef __attribute__((address_space(3))) void* las_ptr;

__device__ __forceinline__ void async_copy16(const void* g, void* l) {
    __builtin_amdgcn_global_load_lds((gas_ptr)g, (las_ptr)l, 16, 0, 0);
}

__device__ __forceinline__ unsigned short f2bf(float f) {
    unsigned int u = __float_as_uint(f);
    u = (u + 0x7fffu + ((u >> 16) & 1u)) >> 16;   // RNE
    return (unsigned short)u;
}
__device__ __forceinline__ float bf2f(unsigned short s) {
    return __uint_as_float(((unsigned int)s) << 16);
}
__device__ __forceinline__ float fexp(float x) { return __expf(x); }
__device__ __forceinline__ float flog(float x) { return __logf(x); }

// ---------------------------------------------------------------------------
// pack_a: blocks [0,180): weights fp32 -> bf16 pre-tiled for the GEMM's LDS
// staging order. Blocks [180, 243): Wm fp32 -> bf16, RE-LAYOUT for em:
// dst entry (kk*10 + c)*32 + a  <-  src entry m*10 + c (m = kk*32+a).
// A half-wave in em (fixed c, a=0..31) then reads 1 KB contiguous per kk.
// Block 0 additionally computes the folded BN scale/bias.
// ---------------------------------------------------------------------------
__global__ __launch_bounds__(256) void pack_a_kernel(
    const float* __restrict__ w_pose, const float* __restrict__ w_a,
    const float* __restrict__ bn_p_g, const float* __restrict__ bn_p_b,
    const float* __restrict__ bn_p_m, const float* __restrict__ bn_p_v,
    const float* __restrict__ bn_a_g, const float* __restrict__ bn_a_b,
    const float* __restrict__ bn_a_m, const float* __restrict__ bn_a_v,
    const float* __restrict__ Wm,
    unsigned short* __restrict__ At, unsigned short* __restrict__ Wmb,
    float* __restrict__ sc, float* __restrict__ bi)
{
    const int blk = blockIdx.x;
    const int t = threadIdx.x;

    if (blk >= NABLK) {                          // ---- Wm bf16 packing ----
        const int chunk = (blk - NABLK) * 256 + t;   // 8 floats per chunk
        if (chunk < 16000) {
            const int e = chunk >> 1, half = chunk & 1;   // entry = (m,c), 16 floats
            const int m = e / 10, c = e - m * 10;
            const int kk = m >> 5, a = m & 31;
            const int de = (kk * 10 + c) * 32 + a;        // transposed entry
            const float4* s4 = reinterpret_cast<const float4*>(Wm + (size_t)chunk * 8);
            float4 x0 = s4[0], x1 = s4[1];
            int4 o;
            o.x = (int)f2bf(x0.x) | ((int)f2bf(x0.y) << 16);
            o.y = (int)f2bf(x0.z) | ((int)f2bf(x0.w) << 16);
            o.z = (int)f2bf(x1.x) | ((int)f2bf(x1.y) << 16);
            o.w = (int)f2bf(x1.z) | ((int)f2bf(x1.w) << 16);
            reinterpret_cast<int4*>(Wmb + ((size_t)de * 2 + half) * 8)[0] = o;
        }
        return;
    }

    const int mblk = blk / NKT;
    if (blk == 0) {
        for (int i = t; i < MPAD; i += 256) {
            float s = 0.f, b = 0.f;
            if (i < 512) {
                s = bn_p_g[i] / sqrtf(bn_p_v[i] + 1e-5f);
                b = bn_p_b[i] - bn_p_m[i] * s;
            } else if (i < 544) {
                const int j = i - 512;
                s = bn_a_g[j] / sqrtf(bn_a_v[j] + 1e-5f);
                b = bn_a_b[j] - bn_a_m[j] * s;
            }
            sc[i] = s; bi[i] = b;
        }
    }

    const int kt = blk - mblk * NKT;
    #pragma unroll
    for (int j = 0; j < 8; ++j) {
        const int c = t + j * 256;               // 0..2047
        const int kc8 = c >> 7, slot = c & 127;
        const int row = mblk * 128 + (slot ^ (kc8 << 2));
        const int k0 = (kt * 16 + kc8) * 8;
        float v[8] = {0.f,0.f,0.f,0.f,0.f,0.f,0.f,0.f};
        if (row < 512) {
            const float4* s4 = reinterpret_cast<const float4*>(w_pose + (size_t)row * KDIM + k0);
            float4 x0 = s4[0], x1 = s4[1];
            v[0]=x0.x; v[1]=x0.y; v[2]=x0.z; v[3]=x0.w;
            v[4]=x1.x; v[5]=x1.y; v[6]=x1.z; v[7]=x1.w;
        } else if (row < 544) {
            const float4* s4 = reinterpret_cast<const float4*>(w_a + (size_t)(row - 512) * KDIM + k0);
            float4 x0 = s4[0], x1 = s4[1];
            v[0]=x0.x; v[1]=x0.y; v[2]=x0.z; v[3]=x0.w;
            v[4]=x1.x; v[5]=x1.y; v[6]=x1.z; v[7]=x1.w;
        }
        int4 o;
        o.x = (int)f2bf(v[0]) | ((int)f2bf(v[1]) << 16);
        o.y = (int)f2bf(v[2]) | ((int)f2bf(v[3]) << 16);
        o.z = (int)f2bf(v[4]) | ((int)f2bf(v[5]) << 16);
        o.w = (int)f2bf(v[6]) | ((int)f2bf(v[7]) << 16);
        reinterpret_cast<int4*>(At + ((((size_t)blk) << 11) + c) * 8)[0] = o;
    }
}

// ---------------------------------------------------------------------------
// pack_b: im2col fp32->bf16, pre-tiled, px-major work order (R10 win).
// ---------------------------------------------------------------------------
__global__ __launch_bounds__(1024) void pack_b_kernel(
    const float* __restrict__ x, unsigned short* __restrict__ Bt)
{
    __shared__ __align__(16) float xs[CIN * 25];
    const int b = blockIdx.x;
    const int t = threadIdx.x;
    const float4* xb = reinterpret_cast<const float4*>(x + (size_t)b * (CIN * 25));
    for (int f4 = t; f4 < (CIN * 25) / 4; f4 += 1024)
        reinterpret_cast<float4*>(xs)[f4] = xb[f4];
    __syncthreads();

    for (int w = t; w < 25 * (KDIM / 8); w += 1024) {
        const int ch = w / 25;                   // k-chunk (px-major order)
        const int px = w - ch * 25;
        const int py = px / 5, qx = px % 5;
        const int k0 = ch * 8;
        unsigned short v[8];
        #pragma unroll
        for (int j = 0; j < 8; ++j) {
            const int k = k0 + j;
            const int ci = k / 9;
            const int kk = k - ci * 9;
            const int dy = kk / 3, dx = kk - dy * 3;
            const int yy = py + dy - 1, xx = qx + dx - 1;
            const bool ok = (yy >= 0) & (yy < 5) & (xx >= 0) & (xx < 5);
            v[j] = ok ? f2bf(xs[ci * 25 + yy * 5 + xx]) : (unsigned short)0;
        }
        int4 o;
        o.x = (int)v[0] | ((int)v[1] << 16);
        o.y = (int)v[2] | ((int)v[3] << 16);
        o.z = (int)v[4] | ((int)v[5] << 16);
        o.w = (int)v[6] | ((int)v[7] << 16);
        const int n = b * 25 + px;
        const int nblk = n >> 7, nr = n & 127;
        const int kt = k0 >> 7;
        const int kc8 = (k0 >> 3) & 15;
        const int c = kc8 * 128 + (nr ^ (kc8 << 2));
        reinterpret_cast<int4*>(Bt + ((((size_t)(nblk * NKT + kt)) << 11) + c) * 8)[0] = o;
    }
}

// ---------------------------------------------------------------------------
// gemm: R11 shape (1024 threads = 4 K-groups x (2x2) waves, 64x64 wave tile,
// BK=128 double-buffered, XCD-swizzled grid, bf16 Cp / fp32 Ca split).
// ---------------------------------------------------------------------------
__global__ __launch_bounds__(1024) void gemm_kernel(
    const unsigned short* __restrict__ At,
    const unsigned short* __restrict__ Bt,
    const float* __restrict__ sc, const float* __restrict__ bi,
    unsigned short* __restrict__ Cp,        // [512][6400] bf16
    float* __restrict__ Ca)                 // [32][6400] fp32
{
    __shared__ __align__(16) unsigned char smem[131072];
    const int t = threadIdx.x;
    const int L = blockIdx.x;
    int mblk, nblk;
    if (L >= 240) { const int i = L - 240; mblk = i >> 1; nblk = 48 + (i & 1); }
    else          { const int q = L / 40, r = L - q * 40;
                    mblk = r >> 3; nblk = q * 8 + (r & 7); }
    const int m0 = mblk * 128, n0 = nblk * 128;
    const int lane = t & 63, w = t >> 6;
    const int g = w >> 2, wq = w & 3;          // 4 K-groups x 4 tile-waves
    const int wm = wq >> 1, wn = wq & 1;
    const int row16 = lane & 15, quad = lane >> 4;

    f32x4 acc[4][4] = {};

    const unsigned short* gAbase = At + (((size_t)mblk * NKT) << 14);
    const unsigned short* gBbase = Bt + (((size_t)nblk * NKT) << 14);

    #define STAGE(kt, s)                                                      \
    {                                                                         \
        unsigned short* As_ = (unsigned short*)(smem + (s) * 65536);          \
        unsigned short* Bs_ = As_ + 16384;                                    \
        const unsigned short* ga = gAbase + ((size_t)(kt) << 14);             \
        const unsigned short* gb = gBbase + ((size_t)(kt) << 14);             \
        _Pragma("unroll")                                                     \
        for (int j = 0; j < 2; ++j) {                                         \
            async_copy16(ga + ((size_t)(j * 1024 + t) << 3),                  \
                         As_ + ((size_t)(j * 1024 + w * 64) << 3));           \
            async_copy16(gb + ((size_t)(j * 1024 + t) << 3),                  \
                         Bs_ + ((size_t)(j * 1024 + w * 64) << 3));           \
        }                                                                     \
    }

    #define COMPUTE(s)                                                        \
    {                                                                         \
        const unsigned short* As_ = (const unsigned short*)(smem + (s) * 65536);\
        const unsigned short* Bs_ = As_ + 16384;                              \
        const int kc8b = g * 4 + quad;                                        \
        const int sw = kc8b << 2;                                             \
        bf16x8 af[4], bfr[4];                                                 \
        _Pragma("unroll")                                                     \
        for (int mt = 0; mt < 4; ++mt)                                        \
            af[mt] = *reinterpret_cast<const bf16x8*>(                        \
                &As_[(size_t)(kc8b * 128 + ((wm * 64 + mt * 16 + row16) ^ sw)) * 8]);\
        _Pragma("unroll")                                                     \
        for (int nt = 0; nt < 4; ++nt)                                        \
            bfr[nt] = *reinterpret_cast<const bf16x8*>(                       \
                &Bs_[(size_t)(kc8b * 128 + ((wn * 64 + nt * 16 + row16) ^ sw)) * 8]);\
        _Pragma("unroll")                                                     \
        for (int mt = 0; mt < 4; ++mt)                                        \
            _Pragma("unroll")                                                 \
            for (int nt = 0; nt < 4; ++nt)                                    \
                acc[mt][nt] = __builtin_amdgcn_mfma_f32_16x16x32_bf16(        \
                    af[mt], bfr[nt], acc[mt][nt], 0, 0, 0);                   \
    }

    STAGE(0, 0);
    for (int kt = 0; kt < NKT; ++kt) {
        __syncthreads();
        if (kt + 1 < NKT) STAGE(kt + 1, (kt + 1) & 1);
        COMPUTE(kt & 1);
    }
    #undef STAGE
    #undef COMPUTE

    // merge the 4 K-groups into group 0 (3 rounds through 64 KB of LDS)
    f32x4* mb = (f32x4*)smem;                 // 4096 f32x4 slots
    #pragma unroll
    for (int r = 1; r < 4; ++r) {
        __syncthreads();
        if (g == r) {
            f32x4* dst = mb + wq * 1024;
            #pragma unroll
            for (int i = 0; i < 16; ++i)
                dst[i * 64 + lane] = acc[i >> 2][i & 3];
        }
        __syncthreads();
        if (g == 0) {
            const f32x4* src = mb + wq * 1024;
            #pragma unroll
            for (int i = 0; i < 16; ++i)
                acc[i >> 2][i & 3] += src[i * 64 + lane];
        }
    }

    if (g == 0) {
        #pragma unroll
        for (int mt = 0; mt < 4; ++mt) {
            const int mbase = m0 + wm * 64 + mt * 16 + quad * 4;
            if (mbase >= 544) continue;
            #pragma unroll
            for (int rg = 0; rg < 4; ++rg) {
                const int m = mbase + rg;
                const float s = sc[m], bbx = bi[m];
                #pragma unroll
                for (int nt = 0; nt < 4; ++nt) {
                    const int n = n0 + wn * 64 + nt * 16 + row16;
                    const float v = fmaf(acc[mt][nt][rg], s, bbx);
                    if (m < 512) Cp[(size_t)m * NTOT + n] = f2bf(v);
                    else Ca[(size_t)(m - 512) * NTOT + n] = 1.f / (1.f + fexp(-v));
                }
            }
        }
    }
}

// ---------------------------------------------------------------------------
// EM routing — R9 structure + coalesced Wm layout + explicit W prefetch
// (depth 1 in phase A, depth 2 in phase S). 640 threads = 2 p-halves (rh)
// x 10 classes x 32 a-lanes, one block per batch.
// Wmb layout: [kk][c][a][16] -> wbase = (c*32+a)*16, stride 5120/kk;
// a half-wave (fixed c) reads 1 KB contiguous per kk.
// ---------------------------------------------------------------------------
__global__ __launch_bounds__(640, 1) void em_kernel(
    const unsigned short* __restrict__ Cp,    // [512][6400] bf16 pose
    const float* __restrict__ Ca,             // [32][6400] fp32 activations
    const unsigned short* __restrict__ Wmb,   // [25][10][32][16] bf16
    const float* __restrict__ beta_u, const float* __restrict__ beta_a,
    float* __restrict__ out)                  // (256,10)
{
    __shared__ __align__(16) float psh[25][32][20];   // 64 KB  pose [kk][a][16+pad]
    __shared__ float aush[800];
    __shared__ float lnqp[2][NCLS][800];              // 64 KB  partial ln_p; [1] reused as rw
    __shared__ float mu_sh[NCLS][16];
    __shared__ float i2s_sh[NCLS][16];
    __shared__ float costp[2][NCLS];
    __shared__ float slgp[2][NCLS];
    __shared__ float Kc_sh[NCLS];
    __shared__ float aout_sh[NCLS];

    const int b = blockIdx.x, t = threadIdx.x;
    const int rh = (t >= 320) ? 1 : 0;
    const int th = t - rh * 320;
    const int c = th >> 5, a = th & 31;
    float* rwsh = &lnqp[1][0][0];                     // aliases lnqp[1]

    // stage pose: Cp row c2 (0..511) -> psh[px][c2>>4][c2&15]
    const unsigned short* pb = Cp + (size_t)b * 25;
    for (int f = t; f < 12800; f += 640) {
        const int c2 = f / 25, px = f - c2 * 25;
        psh[px][c2 >> 4][c2 & 15] = bf2f(pb[(size_t)c2 * NTOT + px]);
    }
    const float* ab = Ca + (size_t)b * 25;
    for (int f = t; f < 800; f += 640) {
        const int ci = f / 25, px = f - ci * 25;
        aush[px * 32 + ci] = ab[(size_t)ci * NTOT + px];
    }
    __syncthreads();

    const float bu = beta_u[c], ba = beta_a[c];
    float muL[8], i2sL[8], KcL = 0.f;
    const unsigned short* wbase = Wmb + ((size_t)(c * 32 + a)) * 16;  // + kk*5120

    // unpack W (2x int4 of bf16) + vote for this thread's p-half
    #define UNPACK_VOTE(w0_, w1_, kk_, vv)                                   \
        {                                                                    \
            float pm[8], wv[16];                                             \
            const float4* pr = reinterpret_cast<const float4*>(&psh[kk_][a][rh * 8]); \
            const float4 p0 = pr[0], p1 = pr[1];                             \
            pm[0]=p0.x; pm[1]=p0.y; pm[2]=p0.z; pm[3]=p0.w;                  \
            pm[4]=p1.x; pm[5]=p1.y; pm[6]=p1.z; pm[7]=p1.w;                  \
            const unsigned int uu[8] = {(unsigned)w0_.x,(unsigned)w0_.y,     \
                (unsigned)w0_.z,(unsigned)w0_.w,(unsigned)w1_.x,             \
                (unsigned)w1_.y,(unsigned)w1_.z,(unsigned)w1_.w};            \
            _Pragma("unroll")                                                \
            for (int i = 0; i < 8; ++i) {                                    \
                wv[2*i]   = __uint_as_float(uu[i] << 16);                    \
                wv[2*i+1] = __uint_as_float(uu[i] & 0xFFFF0000u);            \
            }                                                                \
            _Pragma("unroll")                                                \
            for (int jr = 0; jr < 2; ++jr) {                                 \
                _Pragma("unroll")                                            \
                for (int s = 0; s < 4; ++s) {                                \
                    float av = 0.f;                                          \
                    _Pragma("unroll")                                        \
                    for (int tt = 0; tt < 4; ++tt)                           \
                        av = fmaf(pm[jr*4+tt], wv[tt*4+s], av);              \
                    vv[jr*4+s] = av;                                         \
                }                                                            \
            }                                                                \
        }

    float p95 = 1.f;
    for (int it = 0; it < 3; ++it) {
        p95 *= 0.95f;
        const float lam = 0.01f * (1.f - p95);

        if (it > 0) {
            // ---- phase A: partial ln_p, W prefetch depth 1 ----
            int4 wr0 = *reinterpret_cast<const int4*>(wbase);
            int4 wr1 = *reinterpret_cast<const int4*>(wbase + 8);
            for (int kk = 0; kk < 25; ++kk) {
                const int4 w0 = wr0, w1 = wr1;
                if (kk < 24) {
                    const unsigned short* wn = wbase + (size_t)(kk + 1) * 5120;
                    wr0 = *reinterpret_cast<const int4*>(wn);
                    wr1 = *reinterpret_cast<const int4*>(wn + 8);
                }
                float vv[8];
                UNPACK_VOTE(w0, w1, kk, vv);
                float q = (rh == 0) ? KcL : 0.f;
                #pragma unroll
                for (int j = 0; j < 8; ++j) {
                    const float d = vv[j] - muL[j];
                    q -= d * d * i2sL[j];
                }
                lnqp[rh][c][kk * 32 + a] = q;
            }
            __syncthreads();
            // ---- phase M: merge halves into lnqp[0] ----
            {
                float* l0 = &lnqp[0][0][0];
                const float* l1 = &lnqp[1][0][0];
                for (int f = t; f < 8000; f += 640) l0[f] += l1[f];
            }
            __syncthreads();
            // ---- phase R: softmax over classes, once per (c,m) ----
            {
                const int k0 = rh ? 13 : 0, k1 = rh ? 25 : 13;
                for (int kk = k0; kk < k1; ++kk) {
                    const int m = kk * 32 + a;
                    float qv[NCLS];
                    #pragma unroll
                    for (int cc = 0; cc < NCLS; ++cc) qv[cc] = lnqp[0][cc][m];
                    float mx = qv[0];
                    #pragma unroll
                    for (int cc = 1; cc < NCLS; ++cc) mx = fmaxf(mx, qv[cc]);
                    float den = 0.f;
                    #pragma unroll
                    for (int cc = 0; cc < NCLS; ++cc) den += fexp(qv[cc] - mx);
                    rwsh[c * 800 + m] = fexp(qv[c] - mx) * __builtin_amdgcn_rcpf(den)
                                        * aush[m];
                }
            }
            __syncthreads();
        }

        // ---- phase S: weighted stats, W prefetch depth 2 ----
        float S0 = 0.f, S1[8], S2[8];
        #pragma unroll
        for (int j = 0; j < 8; ++j) { S1[j] = 0.f; S2[j] = 0.f; }

        int4 wA0 = *reinterpret_cast<const int4*>(wbase);
        int4 wA1 = *reinterpret_cast<const int4*>(wbase + 8);
        int4 wB0 = *reinterpret_cast<const int4*>(wbase + 5120);
        int4 wB1 = *reinterpret_cast<const int4*>(wbase + 5120 + 8);
        for (int kk = 0; kk < 25; ++kk) {
            const int4 w0 = wA0, w1 = wA1;
            wA0 = wB0; wA1 = wB1;
            if (kk < 23) {
                const unsigned short* wn = wbase + (size_t)(kk + 2) * 5120;
                wB0 = *reinterpret_cast<const int4*>(wn);
                wB1 = *reinterpret_cast<const int4*>(wn + 8);
            }
            float vv[8];
            UNPACK_VOTE(w0, w1, kk, vv);
            const int m = kk * 32 + a;
            const float rw = (it == 0) ? aush[m] : rwsh[c * 800 + m];
            S0 += rw;
            #pragma unroll
            for (int j = 0; j < 8; ++j) {
                const float rv = rw * vv[j];
                S1[j] += rv;
                S2[j] = fmaf(rv, vv[j], S2[j]);
            }
        }

        // butterfly over the 32 a-lanes (within half-wave)
        #pragma unroll
        for (int off = 16; off >= 1; off >>= 1) {
            S0 += __shfl_xor(S0, off);
            #pragma unroll
            for (int j = 0; j < 8; ++j) {
                S1[j] += __shfl_xor(S1[j], off);
                S2[j] += __shfl_xor(S2[j], off);
            }
        }

        // per-half epilogue (both rh groups hold the SAME full S0)
        if (a == 0) {
            const float s0e = S0 + 1e-12f;
            const float inv = 1.f / s0e;
            float cost_ = 0.f, slg_ = 0.f;
            #pragma unroll
            for (int j = 0; j < 8; ++j) {
                const float mu_ = S1[j] * inv;
                const float sg = (S2[j] - 2.f * mu_ * S1[j] + mu_ * mu_ * S0) * inv
                                 + 1e-12f;
                cost_ += bu + 0.5f * flog(sg);
                slg_ += flog(sg * LN2PI_F);
                mu_sh[c][rh * 8 + j] = mu_;
                i2s_sh[c][rh * 8 + j] = 0.5f / sg;
            }
            costp[rh][c] = cost_;
            slgp[rh][c] = slg_;
        }
        __syncthreads();
        if (a == 0 && rh == 0) {
            const float costsum = (costp[0][c] + costp[1][c]) * S0;
            const float aout = 1.f / (1.f + fexp(-(lam * (ba - costsum))));
            aout_sh[c] = aout;
            Kc_sh[c] = flog(aout) - 0.5f * (slgp[0][c] + slgp[1][c]);
        }
        __syncthreads();
        if (it < 2) {
            #pragma unroll
            for (int j = 0; j < 8; ++j) {
                muL[j] = mu_sh[c][rh * 8 + j];
                i2sL[j] = i2s_sh[c][rh * 8 + j];
            }
            KcL = Kc_sh[c];
        }
    }

    if (t < NCLS) {
        float s = 0.f;
        #pragma unroll
        for (int cc = 0; cc < NCLS; ++cc) s += aout_sh[cc];
        out[b * NCLS + t] = flog(aout_sh[t] / s);
    }
    #undef UNPACK_VOTE
}

// ---------------------------------------------------------------------------
extern "C" void kernel_launch(void* const* d_in, const int* in_sizes, int n_in,
                              void* d_out, int out_size, void* d_ws, size_t ws_size,
                              hipStream_t stream) {
    const float* x      = (const float*)d_in[0];
    const float* w_a    = (const float*)d_in[1];
    const float* w_pose = (const float*)d_in[2];
    const float* bn_a_g = (const float*)d_in[3];
    const float* bn_a_b = (const float*)d_in[4];
    const float* bn_a_m = (const float*)d_in[5];
    const float* bn_a_v = (const float*)d_in[6];
    const float* bn_p_g = (const float*)d_in[7];
    const float* bn_p_b = (const float*)d_in[8];
    const float* bn_p_m = (const float*)d_in[9];
    const float* bn_p_v = (const float*)d_in[10];
    const float* Wm     = (const float*)d_in[11];
    const float* beta_u = (const float*)d_in[12];
    const float* beta_a = (const float*)d_in[13];
    float* out = (float*)d_out;

    char* p = (char*)d_ws;
    unsigned short* At  = (unsigned short*)p;  p += (size_t)MPAD * KDIM * 2;
    unsigned short* Bt  = (unsigned short*)p;  p += (size_t)NTOT * KDIM * 2;
    unsigned short* Wmb = (unsigned short*)p;  p += (size_t)800 * NCLS * 16 * 2;
    unsigned short* Cp  = (unsigned short*)p;  p += (size_t)512 * NTOT * 2;
    float* Ca = (float*)p;                     p += (size_t)32 * NTOT * 4;
    float* sc = (float*)p;                     p += MPAD * 4;
    float* bi = (float*)p;                     p += MPAD * 4;

    pack_a_kernel<<<NABLK + 63, 256, 0, stream>>>(w_pose, w_a,
                                                  bn_p_g, bn_p_b, bn_p_m, bn_p_v,
                                                  bn_a_g, bn_a_b, bn_a_m, bn_a_v,
                                                  Wm, At, Wmb, sc, bi);
    pack_b_kernel<<<256, 1024, 0, stream>>>(x, Bt);
    gemm_kernel<<<250, 1024, 0, stream>>>(At, Bt, sc, bi, Cp, Ca);
    em_kernel<<<256, 640, 0, stream>>>(Cp, Ca, Wmb, beta_u, beta_a, out);
}